// Round 12
// baseline (151.994 us; speedup 1.0000x reference)
//
#include <hip/hip_runtime.h>
#include <hip/hip_bf16.h>

// Problem constants (fixed by setup_inputs): B=8, T=2048, D=1024, positions in [0,64).
#define NB 8
#define NT 2048
#define ND 1024
#define CAP 2048       // max tokens per bucket (worst case all T in one bucket)

typedef unsigned short ushort_t;

__device__ __forceinline__ ushort_t f2bf(float f) {
    __hip_bfloat16 h = __float2bfloat16(f);
    return *reinterpret_cast<ushort_t*>(&h);
}
__device__ __forceinline__ float bf2f(ushort_t u) {
    unsigned int v = ((unsigned int)u) << 16;
    return __int_as_float((int)v);
}

// ---------------------------------------------------------------------------
// Workspace layout (byte offsets):
//   pad    : 64 floats of zeros                                           @ 0
//   G2f    : 128 floats  g2[k] = exp(-(k-63)^2/512), valid k in [0,126]   @ 256
//   cntv   : NB*64 int                                                    @ 768
//   cnth   : NB*64 int                                                    @ 2816
//   invden : NB*64*64 float                                               @ 4864
//   goff   : NB*64 int4   per-bucket wave-group starts                    @ 135936
//   tokv   : NB*64*CAP int   packed (t | posh<<16), bucketed by posv      @ 144128
//   tokh   : NB*64*CAP int   packed (t | posv<<16), bucketed by posh      @ 4338432
//   tokv2  : NB*64*CAP int   tokv regrouped by ph>>4 within bucket        @ 8532736
//   B1     : NB*64*64*1024 bf16   [b][q=ph'][pv][d]                       @ 12727040
// ---------------------------------------------------------------------------
#define OFF_G2     256
#define OFF_CNTV   768
#define OFF_CNTH   2816
#define OFF_INVDEN 4864
#define OFF_GOFF   135936
#define OFF_TOKV   144128
#define OFF_TOKH   4338432
#define OFF_TOKV2  8532736
#define OFF_B1     12727040
#define B1_SLAB    ((size_t)64 * 64 * 1024 * 2)   // bytes per batch slab (8 MB, bf16)

// K1: deterministic CSR bucket lists via wave ballot compaction (no atomics).
// Entries packed: t | (other_axis_pos[t] << 16). Block 0 fills the g table.
__global__ __launch_bounds__(256) void k1_bucket(
    const int* __restrict__ posv, const int* __restrict__ posh,
    int* __restrict__ tokv, int* __restrict__ tokh,
    int* __restrict__ cntv, int* __restrict__ cnth,
    float* __restrict__ gbase)   // = ws base; table lives at gbase+64
{
    int b    = blockIdx.x >> 5;      // NB*32 blocks
    int blk  = blockIdx.x & 31;
    int wave = threadIdx.x >> 6;
    int lane = threadIdx.x & 63;

    if (blockIdx.x == 0 && threadIdx.x < 192) {
        int k = (int)threadIdx.x - 64;     // table index; <0 = pad
        float v = 0.0f;
        if (k >= 0 && k < 127) {
            int r = k - 63;
            v = expf(-(float)(r * r) * (1.0f / 512.0f));
        }
        gbase[threadIdx.x] = v;
    }

    int task   = blk * 4 + wave;                // 0..127
    int bucket = task & 63;
    int use_ph = task >> 6;
    const int* pos  = use_ph ? posh : posv;
    const int* opos = use_ph ? posv : posh;
    int* tok = (use_ph ? tokh : tokv) + ((size_t)(b * 64 + bucket)) * CAP;
    int* cnt = use_ph ? cnth : cntv;

    int vals[32];
#pragma unroll
    for (int k = 0; k < 32; k++) vals[k] = pos[b * NT + k * 64 + lane];

    unsigned long long lmask = (1ull << lane) - 1ull;
    int cursor = 0;
#pragma unroll 4
    for (int k = 0; k < 32; k++) {
        bool hit = (vals[k] == bucket);
        unsigned long long m = __ballot(hit);
        if (hit) {
            int t = k * 64 + lane;
            tok[cursor + __popcll(m & lmask)] = t | (opos[b * NT + t] << 16);
        }
        cursor += (int)__popcll(m);
    }
    if (lane == 0) cnt[b * 64 + bucket] = cursor;
}

// K1b: regroup each (b,pv) bucket by ph>>4 into 4 wave-groups (stable,
// ballot-based, deterministic). Emits tokv2 + per-bucket group starts.
// One bucket per wave; NB*64/4 = 128 blocks.
__global__ __launch_bounds__(256) void k1b_group(
    const int* __restrict__ tokv, const int* __restrict__ cntv,
    int* __restrict__ tokv2, int4* __restrict__ goff)
{
    int bucket = blockIdx.x * 4 + (threadIdx.x >> 6);   // b*64+pv, < NB*64
    int lane   = threadIdx.x & 63;
    int n = cntv[bucket];
    const int* src = tokv + (size_t)bucket * CAP;
    int* dst = tokv2 + (size_t)bucket * CAP;
    unsigned long long lmask = (1ull << lane) - 1ull;

    int cnt0 = 0, cnt1 = 0, cnt2 = 0, cnt3 = 0;
    for (int base = 0; base < n; base += 64) {
        bool valid = base + lane < n;
        int pk = valid ? src[base + lane] : 0;
        int grp = (pk >> 20) & 3;            // ph>>4
        cnt0 += (int)__popcll(__ballot(valid && grp == 0));
        cnt1 += (int)__popcll(__ballot(valid && grp == 1));
        cnt2 += (int)__popcll(__ballot(valid && grp == 2));
        cnt3 += (int)__popcll(__ballot(valid && grp == 3));
    }
    int s0 = 0, s1 = cnt0, s2 = cnt0 + cnt1, s3 = cnt0 + cnt1 + cnt2;
    if (lane == 0) goff[bucket] = make_int4(s0, s1, s2, s3);

    int c0 = s0, c1 = s1, c2 = s2, c3 = s3;
    for (int base = 0; base < n; base += 64) {
        bool valid = base + lane < n;
        int pk = valid ? src[base + lane] : 0;
        int grp = (pk >> 20) & 3;
        unsigned long long m0 = __ballot(valid && grp == 0);
        unsigned long long m1 = __ballot(valid && grp == 1);
        unsigned long long m2 = __ballot(valid && grp == 2);
        unsigned long long m3 = __ballot(valid && grp == 3);
        if (valid) {
            int pos;
            if      (grp == 0) pos = c0 + (int)__popcll(m0 & lmask);
            else if (grp == 1) pos = c1 + (int)__popcll(m1 & lmask);
            else if (grp == 2) pos = c2 + (int)__popcll(m2 & lmask);
            else               pos = c3 + (int)__popcll(m3 & lmask);
            dst[pos] = pk;
        }
        c0 += (int)__popcll(m0); c1 += (int)__popcll(m1);
        c2 += (int)__popcll(m2); c3 += (int)__popcll(m3);
    }
}

// KDEN: denominator table. den[pv][ph] = sum_{j,k} hist[j][k] g(pv-j) g(ph-k).
__global__ __launch_bounds__(256) void kden(
    const int* __restrict__ posv, const int* __restrict__ posh,
    const float* __restrict__ G2f, float* __restrict__ invden, int b0)
{
    int b   = b0 + (blockIdx.x >> 3);
    int phg = blockIdx.x & 7;
    int tid = threadIdx.x;

    __shared__ int   hist[64][64];
    __shared__ float g2s[128];
    __shared__ float tmp[64][8];

#pragma unroll
    for (int k = 0; k < 16; k++) ((int*)hist)[tid + (k << 8)] = 0;
    if (tid < 128) g2s[tid] = G2f[tid];
    __syncthreads();
#pragma unroll
    for (int k = 0; k < 8; k++) {
        int t = (k << 8) + tid;
        atomicAdd(&hist[posv[b * NT + t]][posh[b * NT + t]], 1);
    }
    __syncthreads();
#pragma unroll
    for (int c = 0; c < 2; c++) {
        int cell = (c << 8) + tid;        // 512 cells: 64 j x 8 phl
        int j    = cell >> 3;
        int phl  = cell & 7;
        int ph   = (phg << 3) + phl;
        float s = 0.f;
        for (int k = 0; k < 64; k++)
            s += (float)hist[j][k] * g2s[63 + k - ph];
        tmp[j][phl] = s;
    }
    __syncthreads();
#pragma unroll
    for (int c = 0; c < 2; c++) {
        int cell = (c << 8) + tid;
        int pv   = cell >> 3;
        int phl  = cell & 7;
        int ph   = (phg << 3) + phl;
        float s = 0.f;
        for (int j = 0; j < 64; j++)
            s += g2s[63 + j - pv] * tmp[j][phl];
        invden[(b * 64 + pv) * 64 + ph] = 1.0f / s;
    }
}

// K2: dense h-conv, round-12 structure.
//   Phase A (per-wave private): wave w accumulates ONLY its own tokens
//     (ph>>4 == w, contiguous in tokv2 via goff) into S[ph][d] — ~8 tokens
//     per wave, 4-batched independent loads, no cross-wave serial scan.
//   Phase B (j-tiled conv): rolled outer loop over 4 j-tiles; per tile
//     gw[31]+acc[16]+uv[4] ~ 55 live VGPRs — small enough that the
//     allocator provably keeps it resident (rounds 7/10/11: a 79-value
//     live set gets spilled/re-loaded regardless of launch bounds).
__global__ __launch_bounds__(256, 1) void k2_convh(
    const float* __restrict__ x,
    const int* __restrict__ tokv2, const int* __restrict__ cntv,
    const int4* __restrict__ goff,
    const float* __restrict__ G2f, ushort_t* __restrict__ B1, int b0)
{
    int pv   = blockIdx.x & 63;
    int dc   = (blockIdx.x >> 6) & 15;
    int b    = b0 + (blockIdx.x >> 10);
    int tid  = threadIdx.x;
    int lane = tid & 63;
    int w    = tid >> 6;
    int wq   = w << 4;
    int d0   = dc << 6;

    int bucket = b * 64 + pv;
    int n = cntv[bucket];
    const int* toks = tokv2 + (size_t)bucket * CAP;
    const float* xb = x + (((size_t)b * NT) << 10) + d0 + lane;

    __shared__ float S[64][64];        // S[ph][d]

#pragma unroll
    for (int r = 0; r < 16; r++) ((float*)S)[(r << 8) + tid] = 0.f;
    __syncthreads();

    // Phase A: wave-private token range [gs, ge)
    int4 go = goff[bucket];
    int gs = (w == 0) ? go.x : (w == 1) ? go.y : (w == 2) ? go.z : go.w;
    int ge = (w == 3) ? n   : (w == 0) ? go.y : (w == 1) ? go.z : go.w;

    for (int i = gs; i < ge; i += 4) {
        int pk[4]; float xv[4];
#pragma unroll
        for (int j = 0; j < 4; j++)
            pk[j] = __builtin_amdgcn_readfirstlane((i + j < ge) ? toks[i + j] : 0);
#pragma unroll
        for (int j = 0; j < 4; j++)
            if (i + j < ge) xv[j] = xb[(size_t)(pk[j] & 0xffff) << 10];
#pragma unroll
        for (int j = 0; j < 4; j++)
            if (i + j < ge) S[pk[j] >> 16][lane] += xv[j];
    }
    __syncthreads();

    // Phase B: acc[q] = sum_ph g(wq+q-ph) * S[ph][lane], j-tiled.
    float acc[16];
#pragma unroll
    for (int q = 0; q < 16; q++) acc[q] = 0.f;

#pragma unroll 1
    for (int jt = 0; jt < 64; jt += 16) {
        // gw[k] = G2f[48 + wq - jt + k], k in [0,31); covers q-jj in [-15,15]
        float gw[31];
        const float* gb = G2f + 48 + wq - jt;
#pragma unroll
        for (int k = 0; k < 31; k++) gw[k] = gb[k];
#pragma unroll
        for (int jj = 0; jj < 16; jj += 4) {
            float uv[4];
#pragma unroll
            for (int c = 0; c < 4; c++) uv[c] = S[jt + jj + c][lane];
#pragma unroll
            for (int q = 0; q < 16; q++) {
                float a = acc[q];
#pragma unroll
                for (int c = 0; c < 4; c++)
                    a = fmaf(gw[q - jj - c + 15], uv[c], a);
                acc[q] = a;
            }
        }
    }

    // B1[b][q][pv][d] (bf16), q = wq + qi
    ushort_t* B1p = B1 + (((size_t)(b - b0)) << 22) + (((size_t)wq) << 16)
                  + (((size_t)pv) << 10) + d0 + lane;
#pragma unroll
    for (int q = 0; q < 16; q++)
        B1p[(size_t)q << 16] = f2bf(acc[q]);
}

// K3: dense v-conv fused with token gather + normalization (unchanged —
// at its FMA floor since round 8).
__global__ __launch_bounds__(256, 1) void k3_convv(
    const int* __restrict__ tokh, const int* __restrict__ cnth,
    const float* __restrict__ G2f, const ushort_t* __restrict__ B1,
    const float* __restrict__ invden, float* __restrict__ out, int b0)
{
    int ph   = blockIdx.x & 63;
    int dc   = (blockIdx.x >> 6) & 15;
    int b    = b0 + (blockIdx.x >> 10);
    int tid  = threadIdx.x;
    int lane = tid & 63;
    int w    = tid >> 6;
    int wq   = w << 4;                 // per-lane on purpose (VGPR g loads)
    int d0   = dc << 6;

    int n = cnth[b * 64 + ph];
    if (n == 0) return;               // uniform across block: safe

    __shared__ float u[64][64];       // staged B1 column; reused as y

    const ushort_t* B1p = B1 + (((size_t)(b - b0)) << 22) + (((size_t)ph) << 16)
                        + d0 + lane;
#pragma unroll
    for (int k = 0; k < 16; k++) {
        int j = (k << 2) + w;
        u[j][lane] = bf2f(B1p[(size_t)j << 10]);
    }

    const float* gq = G2f + 63 + wq;   // conv window: gq[-63 .. +15]

    float acc[16];
#pragma unroll
    for (int q = 0; q < 16; q++) acc[q] = 0.f;

    __syncthreads();

#pragma unroll
    for (int j = 0; j < 64; j += 4) {
        float uv[4];
#pragma unroll
        for (int jj = 0; jj < 4; jj++) uv[jj] = u[j + jj][lane];
#pragma unroll
        for (int q = 0; q < 16; q++) {
            float a = acc[q];
#pragma unroll
            for (int jj = 0; jj < 4; jj++)
                a = fmaf(gq[q - (j + jj)], uv[jj], a);
            acc[q] = a;
        }
    }
    __syncthreads();                   // all u reads complete
#pragma unroll
    for (int q = 0; q < 16; q++) u[wq + q][lane] = acc[q];   // y into u's LDS
    __syncthreads();

    const int* toks = tokh + ((size_t)(b * 64 + ph)) * CAP;
    float* outb = out + (((size_t)b * NT) << 10) + d0 + lane;
    const float* ivb = invden + ((b * 64) << 6) + ph;

    // scatter: wave-cyclic chunks of 4 tokens, one int4 meta load per chunk
    int nch = (n + 3) >> 2;
    for (int c = w; c < nch; c += 4) {
        int i0 = c << 2;
        int4 M = *(const int4*)(toks + i0);   // safe past n: ws mapped
        int pk[4];
        pk[0] = __builtin_amdgcn_readfirstlane(M.x);
        pk[1] = __builtin_amdgcn_readfirstlane(M.y);
        pk[2] = __builtin_amdgcn_readfirstlane(M.z);
        pk[3] = __builtin_amdgcn_readfirstlane(M.w);
#pragma unroll
        for (int j = 0; j < 4; j++) {
            if (i0 + j < n) {                 // uniform condition
                int t   = pk[j] & 0xffff;
                int pvt = pk[j] >> 16;
                float iv = ivb[pvt << 6];
                outb[(size_t)t << 10] = u[pvt][lane] * iv;
            }
        }
    }
}

// Safety-net fallback (no workspace needed): direct O(T^2 * D) attention.
__global__ __launch_bounds__(256) void k_naive(
    const float* __restrict__ x, const int* __restrict__ posv,
    const int* __restrict__ posh, float* __restrict__ out)
{
    int t   = blockIdx.x & (NT - 1);
    int b   = blockIdx.x >> 11;
    int tid = threadIdx.x;

    __shared__ float s_w[NT];
    __shared__ float s_red[256];

    int pvt = posv[b * NT + t];
    int pht = posh[b * NT + t];

    float dsum = 0.0f;
    for (int s = tid; s < NT; s += 256) {
        int dv = pvt - posv[b * NT + s];
        int dh = pht - posh[b * NT + s];
        float w = expf(-(float)(dv * dv + dh * dh) * (1.0f / 512.0f));
        s_w[s] = w;
        dsum += w;
    }
    s_red[tid] = dsum;
    __syncthreads();
    for (int off = 128; off > 0; off >>= 1) {
        if (tid < off) s_red[tid] += s_red[tid + off];
        __syncthreads();
    }
    float inv = 1.0f / s_red[0];

    float a0 = 0.f, a1 = 0.f, a2 = 0.f, a3 = 0.f;
    for (int s = 0; s < NT; s++) {
        float w = s_w[s];
        const float* xr = x + (((size_t)(b * NT + s)) << 10);
        a0 = fmaf(w, xr[tid + 0],   a0);
        a1 = fmaf(w, xr[tid + 256], a1);
        a2 = fmaf(w, xr[tid + 512], a2);
        a3 = fmaf(w, xr[tid + 768], a3);
    }
    size_t ob = (((size_t)(b * NT + t)) << 10) + tid;
    out[ob + 0]   = a0 * inv;
    out[ob + 256] = a1 * inv;
    out[ob + 512] = a2 * inv;
    out[ob + 768] = a3 * inv;
}

extern "C" void kernel_launch(void* const* d_in, const int* in_sizes, int n_in,
                              void* d_out, int out_size, void* d_ws, size_t ws_size,
                              hipStream_t stream) {
    const float* x    = (const float*)d_in[0];
    const int*   posv = (const int*)d_in[1];
    const int*   posh = (const int*)d_in[2];
    float*       out  = (float*)d_out;

    char* ws = (char*)d_ws;
    float*    gbase  = (float*)ws;               // pad + table
    float*    G2f    = (float*)(ws + OFF_G2);
    int*      cntv   = (int*)(ws + OFF_CNTV);
    int*      cnth   = (int*)(ws + OFF_CNTH);
    float*    invden = (float*)(ws + OFF_INVDEN);
    int4*     goff   = (int4*)(ws + OFF_GOFF);
    int*      tokv   = (int*)(ws + OFF_TOKV);
    int*      tokh   = (int*)(ws + OFF_TOKH);
    int*      tokv2  = (int*)(ws + OFF_TOKV2);
    ushort_t* B1     = (ushort_t*)(ws + OFF_B1);

    const size_t needFull = (size_t)OFF_B1 + (size_t)NB * B1_SLAB;   // ~80 MB
    const size_t needLoop = (size_t)OFF_B1 + B1_SLAB;                // ~21 MB

    if (ws_size >= needFull) {
        k1_bucket<<<NB * 32, 256, 0, stream>>>(posv, posh, tokv, tokh, cntv, cnth, gbase);
        k1b_group<<<NB * 16, 256, 0, stream>>>(tokv, cntv, tokv2, goff);
        kden<<<NB * 8, 256, 0, stream>>>(posv, posh, G2f, invden, 0);
        k2_convh<<<NB * 1024, 256, 0, stream>>>(x, tokv2, cntv, goff, G2f, B1, 0);
        k3_convv<<<NB * 1024, 256, 0, stream>>>(tokh, cnth, G2f, B1, invden, out, 0);
    } else if (ws_size >= needLoop) {
        k1_bucket<<<NB * 32, 256, 0, stream>>>(posv, posh, tokv, tokh, cntv, cnth, gbase);
        k1b_group<<<NB * 16, 256, 0, stream>>>(tokv, cntv, tokv2, goff);
        for (int b = 0; b < NB; b++) {
            kden<<<8, 256, 0, stream>>>(posv, posh, G2f, invden, b);
            k2_convh<<<1024, 256, 0, stream>>>(x, tokv2, cntv, goff, G2f, B1, b);
            k3_convv<<<1024, 256, 0, stream>>>(tokh, cnth, G2f, B1, invden, out, b);
        }
    } else {
        k_naive<<<NB * NT, 256, 0, stream>>>(x, posv, posh, out);
    }
}

// Round 13
// 92.070 us; speedup vs baseline: 1.6508x; 1.6508x over previous
//
#include <hip/hip_runtime.h>
#include <hip/hip_bf16.h>

// Problem constants (fixed by setup_inputs): B=8, T=2048, D=1024, positions in [0,64).
#define NB 8
#define NT 2048
#define ND 1024
#define CAP 2048

typedef unsigned short ushort_t;
using short8 = __attribute__((ext_vector_type(8))) short;   // 8 bf16 (4 VGPR)
using f32x4  = __attribute__((ext_vector_type(4))) float;   // MFMA accum

__device__ __forceinline__ ushort_t f2bf(float f) {
    __hip_bfloat16 h = __float2bfloat16(f);
    return *reinterpret_cast<ushort_t*>(&h);
}
__device__ __forceinline__ float bf2f(ushort_t u) {
    unsigned int v = ((unsigned int)u) << 16;
    return __int_as_float((int)v);
}

// MFMA operand K-slot mapping for 16x16x32 bf16 (two 16x16x16 halves).
// NOTE: any consistent bijection works — K is the reduction axis, and the
// same formula is used for the A-fragment table (k1) and B-fragment LDS
// reads (k2/k3), so a permutation error cancels identically.
//   k(g, i) = (i>>2)*16 + 4*g + (i&3),  g = lane>>4
// A: row m = lane&15. B: col n = lane&15. C/D: col=lane&15,
// row=4*(lane>>4)+reg [HW-verified mapping].

// ---------------------------------------------------------------------------
// Workspace layout (byte offsets):
//   pad     : zeros (legacy)                                        @ 0
//   G2f     : 128 fp32  g(k-63), valid k in [0,126]                 @ 256
//   AfragHi : 4*2*64*8 bf16  A-fragment table, hi part              @ 768
//   AfragLo : same, lo part (g - hi)                                @ 8960
//   cntv    : NB*64 int                                             @ 17152
//   cnth    : NB*64 int                                             @ 19200
//   invden  : NB*64*64 fp32                                         @ 21248
//   goff    : NB*64 int4  per-bucket ph-group starts                @ 152320
//   tokv    : NB*64*CAP int  (t | posh<<16) by posv                 @ 160512
//   tokh    : NB*64*CAP int  (t | posv<<16) by posh                 @ 4354816
//   tokv2   : tokv regrouped by ph>>4                               @ 8549120
//   B1      : NB*64*64*1024 bf16  [b][q][pv][d]                     @ 12743424
// ---------------------------------------------------------------------------
#define OFF_G2     256
#define OFF_AFH    768
#define OFF_AFL    8960
#define OFF_CNTV   17152
#define OFF_CNTH   19200
#define OFF_INVDEN 21248
#define OFF_GOFF   152320
#define OFF_TOKV   160512
#define OFF_TOKH   4354816
#define OFF_TOKV2  8549120
#define OFF_B1     12743424
#define B1_SLAB    ((size_t)64 * 64 * 1024 * 2)   // 8 MB per batch (bf16)

// K1: deterministic CSR bucket lists via wave ballot compaction. Block 0
// also builds the fp32 g table AND the MFMA A-fragment tables (hi/lo bf16).
__global__ __launch_bounds__(256) void k1_bucket(
    const int* __restrict__ posv, const int* __restrict__ posh,
    int* __restrict__ tokv, int* __restrict__ tokh,
    int* __restrict__ cntv, int* __restrict__ cnth,
    float* __restrict__ gbase, ushort_t* __restrict__ AfH,
    ushort_t* __restrict__ AfL)
{
    int b    = blockIdx.x >> 5;
    int blk  = blockIdx.x & 31;
    int wave = threadIdx.x >> 6;
    int lane = threadIdx.x & 63;

    if (blockIdx.x == 0) {
        if (threadIdx.x < 192) {
            int k = (int)threadIdx.x - 64;
            float v = 0.0f;
            if (k >= 0 && k < 127) {
                int r = k - 63;
                v = expf(-(float)(r * r) * (1.0f / 512.0f));
            }
            gbase[threadIdx.x] = v;
        }
        // A-fragment tables: entry (w, ks, lane, i) = g(q - k), split hi/lo.
#pragma unroll
        for (int p = 0; p < 16; p++) {
            int pos = (p << 8) + (int)threadIdx.x;   // 0..4095
            int i   = pos & 7;
            int ln  = (pos >> 3) & 63;
            int ks  = (pos >> 9) & 1;
            int w   = pos >> 10;
            int q   = (w << 4) + (ln & 15);
            int k   = (ks << 5) + ((i >> 2) << 4) + ((ln >> 4) << 2) + (i & 3);
            int dlt = q - k;
            float g = expf(-(float)(dlt * dlt) * (1.0f / 512.0f));
            ushort_t hi = f2bf(g);
            AfH[pos] = hi;
            AfL[pos] = f2bf(g - bf2f(hi));
        }
    }

    int task   = blk * 4 + wave;
    int bucket = task & 63;
    int use_ph = task >> 6;
    const int* pos  = use_ph ? posh : posv;
    const int* opos = use_ph ? posv : posh;
    int* tok = (use_ph ? tokh : tokv) + ((size_t)(b * 64 + bucket)) * CAP;
    int* cnt = use_ph ? cnth : cntv;

    int vals[32];
#pragma unroll
    for (int k = 0; k < 32; k++) vals[k] = pos[b * NT + k * 64 + lane];

    unsigned long long lmask = (1ull << lane) - 1ull;
    int cursor = 0;
#pragma unroll 4
    for (int k = 0; k < 32; k++) {
        bool hit = (vals[k] == bucket);
        unsigned long long m = __ballot(hit);
        if (hit) {
            int t = k * 64 + lane;
            tok[cursor + __popcll(m & lmask)] = t | (opos[b * NT + t] << 16);
        }
        cursor += (int)__popcll(m);
    }
    if (lane == 0) cnt[b * 64 + bucket] = cursor;
}

// K1b: regroup each (b,pv) bucket by ph>>4 into 4 wave-groups (stable,
// deterministic). One bucket per wave.
__global__ __launch_bounds__(256) void k1b_group(
    const int* __restrict__ tokv, const int* __restrict__ cntv,
    int* __restrict__ tokv2, int4* __restrict__ goff)
{
    int bucket = blockIdx.x * 4 + (threadIdx.x >> 6);
    int lane   = threadIdx.x & 63;
    int n = cntv[bucket];
    const int* src = tokv + (size_t)bucket * CAP;
    int* dst = tokv2 + (size_t)bucket * CAP;
    unsigned long long lmask = (1ull << lane) - 1ull;

    int cnt0 = 0, cnt1 = 0, cnt2 = 0, cnt3 = 0;
    for (int base = 0; base < n; base += 64) {
        bool valid = base + lane < n;
        int pk = valid ? src[base + lane] : 0;
        int grp = (pk >> 20) & 3;
        cnt0 += (int)__popcll(__ballot(valid && grp == 0));
        cnt1 += (int)__popcll(__ballot(valid && grp == 1));
        cnt2 += (int)__popcll(__ballot(valid && grp == 2));
        cnt3 += (int)__popcll(__ballot(valid && grp == 3));
    }
    int s1 = cnt0, s2 = cnt0 + cnt1, s3 = cnt0 + cnt1 + cnt2;
    if (lane == 0) goff[bucket] = make_int4(0, s1, s2, s3);

    int c0 = 0, c1 = s1, c2 = s2, c3 = s3;
    for (int base = 0; base < n; base += 64) {
        bool valid = base + lane < n;
        int pk = valid ? src[base + lane] : 0;
        int grp = (pk >> 20) & 3;
        unsigned long long m0 = __ballot(valid && grp == 0);
        unsigned long long m1 = __ballot(valid && grp == 1);
        unsigned long long m2 = __ballot(valid && grp == 2);
        unsigned long long m3 = __ballot(valid && grp == 3);
        if (valid) {
            int p;
            if      (grp == 0) p = c0 + (int)__popcll(m0 & lmask);
            else if (grp == 1) p = c1 + (int)__popcll(m1 & lmask);
            else if (grp == 2) p = c2 + (int)__popcll(m2 & lmask);
            else               p = c3 + (int)__popcll(m3 & lmask);
            dst[p] = pk;
        }
        c0 += (int)__popcll(m0); c1 += (int)__popcll(m1);
        c2 += (int)__popcll(m2); c3 += (int)__popcll(m3);
    }
}

// KDEN: denominator table (fp32 exact g). Unchanged.
__global__ __launch_bounds__(256) void kden(
    const int* __restrict__ posv, const int* __restrict__ posh,
    const float* __restrict__ G2f, float* __restrict__ invden, int b0)
{
    int b   = b0 + (blockIdx.x >> 3);
    int phg = blockIdx.x & 7;
    int tid = threadIdx.x;

    __shared__ int   hist[64][64];
    __shared__ float g2s[128];
    __shared__ float tmp[64][8];

#pragma unroll
    for (int k = 0; k < 16; k++) ((int*)hist)[tid + (k << 8)] = 0;
    if (tid < 128) g2s[tid] = G2f[tid];
    __syncthreads();
#pragma unroll
    for (int k = 0; k < 8; k++) {
        int t = (k << 8) + tid;
        atomicAdd(&hist[posv[b * NT + t]][posh[b * NT + t]], 1);
    }
    __syncthreads();
#pragma unroll
    for (int c = 0; c < 2; c++) {
        int cell = (c << 8) + tid;
        int j    = cell >> 3;
        int phl  = cell & 7;
        int ph   = (phg << 3) + phl;
        float s = 0.f;
        for (int k = 0; k < 64; k++)
            s += (float)hist[j][k] * g2s[63 + k - ph];
        tmp[j][phl] = s;
    }
    __syncthreads();
#pragma unroll
    for (int c = 0; c < 2; c++) {
        int cell = (c << 8) + tid;
        int pv   = cell >> 3;
        int phl  = cell & 7;
        int ph   = (phg << 3) + phl;
        float s = 0.f;
        for (int j = 0; j < 64; j++)
            s += g2s[63 + j - pv] * tmp[j][phl];
        invden[(b * 64 + pv) * 64 + ph] = 1.0f / s;
    }
}

// B-fragment load: 8 bf16 at k = ks*32 + {4g..4g+3, 16+4g..16+4g+3}, row n.
__device__ __forceinline__ short8 ldsBfrag(const ushort_t* rowp, int ks, int g4) {
    const ushort_t* p = rowp + (ks << 5) + g4;
    uint2 lo = *(const uint2*)(p);
    uint2 hi = *(const uint2*)(p + 16);
    uint4 pk; pk.x = lo.x; pk.y = lo.y; pk.z = hi.x; pk.w = hi.y;
    return __builtin_bit_cast(short8, pk);
}

// K2: h-conv via MFMA (round-12 pivot — 6 rounds of VALU-conv lost to
// register-allocator re-serialization of the g-window; MFMA needs no
// window: A-frags 16 VGPR from a precomputed table, acc 4 VGPR/tile).
//   Phase A: wave-private scatter of bucket tokens into S[d][ph] fp32 LDS
//            (transposed +pad 65 -> conflict-free RMW).
//   Convert: S -> bf16 S16[d][ph] (+pad 68 -> aligned b64 frag reads).
//   Phase B: Y[q][d] = (Ghi+Glo)·S16 : 16 MFMA/wave; store bf16 B1.
__global__ __launch_bounds__(256) void k2_convh(
    const float* __restrict__ x,
    const int* __restrict__ tokv2, const int* __restrict__ cntv,
    const int4* __restrict__ goff,
    const ushort_t* __restrict__ AfH, const ushort_t* __restrict__ AfL,
    ushort_t* __restrict__ B1, int b0)
{
    int pv   = blockIdx.x & 63;
    int dc   = (blockIdx.x >> 6) & 15;
    int b    = b0 + (blockIdx.x >> 10);
    int tid  = threadIdx.x;
    int lane = tid & 63;
    int w    = tid >> 6;
    int d0   = dc << 6;

    __shared__ float    S[64][65];     // S[d][ph] fp32 accum
    __shared__ ushort_t S16[64][68];   // bf16, b64-aligned rows

#pragma unroll
    for (int k = 0; k < 17; k++) {
        int idx = (k << 8) + tid;
        if (idx < 64 * 65) ((float*)S)[idx] = 0.f;
    }
    __syncthreads();

    int bucket = (b << 6) + pv;
    int n = cntv[bucket];
    const int* toks = tokv2 + (size_t)bucket * CAP;
    const float* xb = x + (((size_t)b * NT) << 10) + d0 + lane;

    int4 go = goff[bucket];
    int gs = (w == 0) ? go.x : (w == 1) ? go.y : (w == 2) ? go.z : go.w;
    int ge = (w == 3) ? n   : (w == 0) ? go.y : (w == 1) ? go.z : go.w;

    for (int i = gs; i < ge; i += 4) {
        int pk[4]; float xv[4];
#pragma unroll
        for (int j = 0; j < 4; j++)
            pk[j] = __builtin_amdgcn_readfirstlane((i + j < ge) ? toks[i + j] : 0);
#pragma unroll
        for (int j = 0; j < 4; j++)
            if (i + j < ge) xv[j] = xb[(size_t)(pk[j] & 0xffff) << 10];
#pragma unroll
        for (int j = 0; j < 4; j++)
            if (i + j < ge) S[lane][pk[j] >> 16] += xv[j];
    }
    __syncthreads();

    {
        int r  = tid & 63;
        int c0 = (tid >> 6) << 4;
#pragma unroll
        for (int c = 0; c < 16; c++)
            S16[r][c0 + c] = f2bf(S[r][c0 + c]);
    }
    __syncthreads();

    short8 ahi[2], alo[2];
#pragma unroll
    for (int ks = 0; ks < 2; ks++) {
        int idx = ((((w << 1) + ks) << 6) + lane) << 3;
        ahi[ks] = *(const short8*)(AfH + idx);
        alo[ks] = *(const short8*)(AfL + idx);
    }
    int g4 = (lane >> 4) << 2;
    int qbase = (w << 4) + g4;         // D rows: qbase + reg
    ushort_t* B1p = B1 + (((size_t)(b - b0)) << 22) + (((size_t)pv) << 10) + d0;

#pragma unroll
    for (int nt = 0; nt < 4; nt++) {
        const ushort_t* rowp = &S16[(nt << 4) + (lane & 15)][0];
        f32x4 acc = {0.f, 0.f, 0.f, 0.f};
#pragma unroll
        for (int ks = 0; ks < 2; ks++) {
            short8 bf = ldsBfrag(rowp, ks, g4);
            acc = __builtin_amdgcn_mfma_f32_16x16x32_bf16(ahi[ks], bf, acc, 0, 0, 0);
            acc = __builtin_amdgcn_mfma_f32_16x16x32_bf16(alo[ks], bf, acc, 0, 0, 0);
        }
#pragma unroll
        for (int reg = 0; reg < 4; reg++)
            B1p[((size_t)(qbase + reg) << 16) + (nt << 4) + (lane & 15)] = f2bf(acc[reg]);
    }
}

// K3: v-conv via MFMA + token scatter. Stage bf16 B1 column transposed
// into LDS (direct copy, no convert), MFMA y = (Ghi+Glo)·u, park y fp32,
// scatter out[t][d] = y[pv_t][d] * invden.
__global__ __launch_bounds__(256) void k3_convv(
    const int* __restrict__ tokh, const int* __restrict__ cnth,
    const ushort_t* __restrict__ AfH, const ushort_t* __restrict__ AfL,
    const ushort_t* __restrict__ B1, const float* __restrict__ invden,
    float* __restrict__ out, int b0)
{
    int ph   = blockIdx.x & 63;
    int dc   = (blockIdx.x >> 6) & 15;
    int b    = b0 + (blockIdx.x >> 10);
    int tid  = threadIdx.x;
    int lane = tid & 63;
    int w    = tid >> 6;
    int d0   = dc << 6;

    int n = cnth[(b << 6) + ph];
    if (n == 0) return;               // uniform across block

    __shared__ ushort_t u16[64][68];  // u16[d][j]
    __shared__ float    y[64][65];

    const ushort_t* B1b = B1 + (((size_t)(b - b0)) << 22) + (((size_t)ph) << 16)
                        + d0 + lane;
#pragma unroll
    for (int it = 0; it < 16; it++) {
        int j = (w << 4) + it;
        u16[lane][j] = B1b[(size_t)j << 10];
    }
    __syncthreads();

    short8 ahi[2], alo[2];
#pragma unroll
    for (int ks = 0; ks < 2; ks++) {
        int idx = ((((w << 1) + ks) << 6) + lane) << 3;
        ahi[ks] = *(const short8*)(AfH + idx);
        alo[ks] = *(const short8*)(AfL + idx);
    }
    int g4 = (lane >> 4) << 2;
    int qbase = (w << 4) + g4;

#pragma unroll
    for (int nt = 0; nt < 4; nt++) {
        const ushort_t* rowp = &u16[(nt << 4) + (lane & 15)][0];
        f32x4 acc = {0.f, 0.f, 0.f, 0.f};
#pragma unroll
        for (int ks = 0; ks < 2; ks++) {
            short8 bf = ldsBfrag(rowp, ks, g4);
            acc = __builtin_amdgcn_mfma_f32_16x16x32_bf16(ahi[ks], bf, acc, 0, 0, 0);
            acc = __builtin_amdgcn_mfma_f32_16x16x32_bf16(alo[ks], bf, acc, 0, 0, 0);
        }
#pragma unroll
        for (int reg = 0; reg < 4; reg++)
            y[qbase + reg][(nt << 4) + (lane & 15)] = acc[reg];
    }
    __syncthreads();

    const int* toks = tokh + ((size_t)((b << 6) + ph)) * CAP;
    float* outb = out + (((size_t)b * NT) << 10) + d0 + lane;
    const float* ivb = invden + ((b << 6) << 6) + ph;

    int nch = (n + 3) >> 2;
    for (int c = w; c < nch; c += 4) {
        int i0 = c << 2;
        int4 M = *(const int4*)(toks + i0);   // safe past n: ws mapped
        int pk[4];
        pk[0] = __builtin_amdgcn_readfirstlane(M.x);
        pk[1] = __builtin_amdgcn_readfirstlane(M.y);
        pk[2] = __builtin_amdgcn_readfirstlane(M.z);
        pk[3] = __builtin_amdgcn_readfirstlane(M.w);
#pragma unroll
        for (int j = 0; j < 4; j++) {
            if (i0 + j < n) {
                int t   = pk[j] & 0xffff;
                int pvt = pk[j] >> 16;
                float iv = ivb[pvt << 6];
                outb[(size_t)t << 10] = y[pvt][lane] * iv;
            }
        }
    }
}

// Safety-net fallback (no workspace needed): direct O(T^2 * D) attention.
__global__ __launch_bounds__(256) void k_naive(
    const float* __restrict__ x, const int* __restrict__ posv,
    const int* __restrict__ posh, float* __restrict__ out)
{
    int t   = blockIdx.x & (NT - 1);
    int b   = blockIdx.x >> 11;
    int tid = threadIdx.x;

    __shared__ float s_w[NT];
    __shared__ float s_red[256];

    int pvt = posv[b * NT + t];
    int pht = posh[b * NT + t];

    float dsum = 0.0f;
    for (int s = tid; s < NT; s += 256) {
        int dv = pvt - posv[b * NT + s];
        int dh = pht - posh[b * NT + s];
        float w = expf(-(float)(dv * dv + dh * dh) * (1.0f / 512.0f));
        s_w[s] = w;
        dsum += w;
    }
    s_red[tid] = dsum;
    __syncthreads();
    for (int off = 128; off > 0; off >>= 1) {
        if (tid < off) s_red[tid] += s_red[tid + off];
        __syncthreads();
    }
    float inv = 1.0f / s_red[0];

    float a0 = 0.f, a1 = 0.f, a2 = 0.f, a3 = 0.f;
    for (int s = 0; s < NT; s++) {
        float w = s_w[s];
        const float* xr = x + (((size_t)(b * NT + s)) << 10);
        a0 = fmaf(w, xr[tid + 0],   a0);
        a1 = fmaf(w, xr[tid + 256], a1);
        a2 = fmaf(w, xr[tid + 512], a2);
        a3 = fmaf(w, xr[tid + 768], a3);
    }
    size_t ob = (((size_t)(b * NT + t)) << 10) + tid;
    out[ob + 0]   = a0 * inv;
    out[ob + 256] = a1 * inv;
    out[ob + 512] = a2 * inv;
    out[ob + 768] = a3 * inv;
}

extern "C" void kernel_launch(void* const* d_in, const int* in_sizes, int n_in,
                              void* d_out, int out_size, void* d_ws, size_t ws_size,
                              hipStream_t stream) {
    const float* x    = (const float*)d_in[0];
    const int*   posv = (const int*)d_in[1];
    const int*   posh = (const int*)d_in[2];
    float*       out  = (float*)d_out;

    char* ws = (char*)d_ws;
    float*    gbase  = (float*)ws;
    float*    G2f    = (float*)(ws + OFF_G2);
    ushort_t* AfH    = (ushort_t*)(ws + OFF_AFH);
    ushort_t* AfL    = (ushort_t*)(ws + OFF_AFL);
    int*      cntv   = (int*)(ws + OFF_CNTV);
    int*      cnth   = (int*)(ws + OFF_CNTH);
    float*    invden = (float*)(ws + OFF_INVDEN);
    int4*     goff   = (int4*)(ws + OFF_GOFF);
    int*      tokv   = (int*)(ws + OFF_TOKV);
    int*      tokh   = (int*)(ws + OFF_TOKH);
    int*      tokv2  = (int*)(ws + OFF_TOKV2);
    ushort_t* B1     = (ushort_t*)(ws + OFF_B1);

    const size_t needFull = (size_t)OFF_B1 + (size_t)NB * B1_SLAB;   // ~80 MB
    const size_t needLoop = (size_t)OFF_B1 + B1_SLAB;                // ~21 MB

    if (ws_size >= needFull) {
        k1_bucket<<<NB * 32, 256, 0, stream>>>(posv, posh, tokv, tokh, cntv, cnth,
                                               gbase, AfH, AfL);
        k1b_group<<<NB * 16, 256, 0, stream>>>(tokv, cntv, tokv2, goff);
        kden<<<NB * 8, 256, 0, stream>>>(posv, posh, G2f, invden, 0);
        k2_convh<<<NB * 1024, 256, 0, stream>>>(x, tokv2, cntv, goff, AfH, AfL, B1, 0);
        k3_convv<<<NB * 1024, 256, 0, stream>>>(tokh, cnth, AfH, AfL, B1, invden, out, 0);
    } else if (ws_size >= needLoop) {
        k1_bucket<<<NB * 32, 256, 0, stream>>>(posv, posh, tokv, tokh, cntv, cnth,
                                               gbase, AfH, AfL);
        k1b_group<<<NB * 16, 256, 0, stream>>>(tokv, cntv, tokv2, goff);
        for (int b = 0; b < NB; b++) {
            kden<<<8, 256, 0, stream>>>(posv, posh, G2f, invden, b);
            k2_convh<<<1024, 256, 0, stream>>>(x, tokv2, cntv, goff, AfH, AfL, B1, b);
            k3_convv<<<1024, 256, 0, stream>>>(tokh, cnth, AfH, AfL, B1, invden, out, b);
        }
    } else {
        k_naive<<<NB * NT, 256, 0, stream>>>(x, posv, posh, out);
    }
}

// Round 14
// 81.070 us; speedup vs baseline: 1.8749x; 1.1357x over previous
//
#include <hip/hip_runtime.h>
#include <hip/hip_bf16.h>

// Problem constants (fixed by setup_inputs): B=8, T=2048, D=1024, positions in [0,64).
#define NB 8
#define NT 2048
#define ND 1024
#define CAP 2048

typedef unsigned short ushort_t;
using short8 = __attribute__((ext_vector_type(8))) short;   // 8 bf16 (4 VGPR)
using f32x4  = __attribute__((ext_vector_type(4))) float;   // MFMA accum

__device__ __forceinline__ ushort_t f2bf(float f) {
    __hip_bfloat16 h = __float2bfloat16(f);
    return *reinterpret_cast<ushort_t*>(&h);
}
__device__ __forceinline__ float bf2f(ushort_t u) {
    unsigned int v = ((unsigned int)u) << 16;
    return __int_as_float((int)v);
}

// MFMA operand K-slot mapping for 16x16x32 bf16: k(g,i) = (i>>2)*16+4g+(i&3),
// g = lane>>4. Consistent on A-table (k1) and B-reads (k2/k3) -> any
// permutation error cancels over the reduction axis. C/D: col=lane&15,
// row=4*(lane>>4)+reg [HW-verified]. (Validated: round-13 absmax unchanged.)

// ---------------------------------------------------------------------------
// Workspace layout (byte offsets):
//   pad     : zeros (legacy)                                        @ 0
//   G2f     : 128 fp32  g(k-63), valid k in [0,126]                 @ 256
//   AfragHi : 4*2*64*8 bf16  A-fragment table, hi part              @ 768
//   AfragLo : same, lo part (g - hi)                                @ 8960
//   cntv    : NB*64 int                                             @ 17152
//   cnth    : NB*64 int                                             @ 19200
//   invden  : NB*64*64 fp32                                         @ 21248
//   goff    : NB*64 int4  per-bucket ph-group starts                @ 152320
//   tokv    : NB*64*CAP int  (t | posh<<16) by posv                 @ 160512
//   tokh    : NB*64*CAP int  (t | posv<<16) by posh                 @ 4354816
//   tokv2   : tokv regrouped by ph>>4                               @ 8549120
//   B1      : NB*64*64*1024 bf16  [b][q][pv][d]                     @ 12743424
// ---------------------------------------------------------------------------
#define OFF_G2     256
#define OFF_AFH    768
#define OFF_AFL    8960
#define OFF_CNTV   17152
#define OFF_CNTH   19200
#define OFF_INVDEN 21248
#define OFF_GOFF   152320
#define OFF_TOKV   160512
#define OFF_TOKH   4354816
#define OFF_TOKV2  8549120
#define OFF_B1     12743424
#define B1_SLAB    ((size_t)64 * 64 * 1024 * 2)   // 8 MB per batch (bf16)

// K1: deterministic CSR bucket lists via wave ballot compaction. Block 0
// also builds the fp32 g table AND the MFMA A-fragment tables (hi/lo bf16).
__global__ __launch_bounds__(256) void k1_bucket(
    const int* __restrict__ posv, const int* __restrict__ posh,
    int* __restrict__ tokv, int* __restrict__ tokh,
    int* __restrict__ cntv, int* __restrict__ cnth,
    float* __restrict__ gbase, ushort_t* __restrict__ AfH,
    ushort_t* __restrict__ AfL)
{
    int b    = blockIdx.x >> 5;
    int blk  = blockIdx.x & 31;
    int wave = threadIdx.x >> 6;
    int lane = threadIdx.x & 63;

    if (blockIdx.x == 0) {
        if (threadIdx.x < 192) {
            int k = (int)threadIdx.x - 64;
            float v = 0.0f;
            if (k >= 0 && k < 127) {
                int r = k - 63;
                v = expf(-(float)(r * r) * (1.0f / 512.0f));
            }
            gbase[threadIdx.x] = v;
        }
#pragma unroll
        for (int p = 0; p < 16; p++) {
            int pos = (p << 8) + (int)threadIdx.x;   // 0..4095
            int i   = pos & 7;
            int ln  = (pos >> 3) & 63;
            int ks  = (pos >> 9) & 1;
            int w   = pos >> 10;
            int q   = (w << 4) + (ln & 15);
            int k   = (ks << 5) + ((i >> 2) << 4) + ((ln >> 4) << 2) + (i & 3);
            int dlt = q - k;
            float g = expf(-(float)(dlt * dlt) * (1.0f / 512.0f));
            ushort_t hi = f2bf(g);
            AfH[pos] = hi;
            AfL[pos] = f2bf(g - bf2f(hi));
        }
    }

    int task   = blk * 4 + wave;
    int bucket = task & 63;
    int use_ph = task >> 6;
    const int* pos  = use_ph ? posh : posv;
    const int* opos = use_ph ? posv : posh;
    int* tok = (use_ph ? tokh : tokv) + ((size_t)(b * 64 + bucket)) * CAP;
    int* cnt = use_ph ? cnth : cntv;

    int vals[32];
#pragma unroll
    for (int k = 0; k < 32; k++) vals[k] = pos[b * NT + k * 64 + lane];

    unsigned long long lmask = (1ull << lane) - 1ull;
    int cursor = 0;
#pragma unroll 4
    for (int k = 0; k < 32; k++) {
        bool hit = (vals[k] == bucket);
        unsigned long long m = __ballot(hit);
        if (hit) {
            int t = k * 64 + lane;
            tok[cursor + __popcll(m & lmask)] = t | (opos[b * NT + t] << 16);
        }
        cursor += (int)__popcll(m);
    }
    if (lane == 0) cnt[b * 64 + bucket] = cursor;
}

// K1b: regroup each (b,pv) bucket by ph>>4 into 4 wave-groups (stable,
// deterministic). One bucket per wave.
__global__ __launch_bounds__(256) void k1b_group(
    const int* __restrict__ tokv, const int* __restrict__ cntv,
    int* __restrict__ tokv2, int4* __restrict__ goff)
{
    int bucket = blockIdx.x * 4 + (threadIdx.x >> 6);
    int lane   = threadIdx.x & 63;
    int n = cntv[bucket];
    const int* src = tokv + (size_t)bucket * CAP;
    int* dst = tokv2 + (size_t)bucket * CAP;
    unsigned long long lmask = (1ull << lane) - 1ull;

    int cnt0 = 0, cnt1 = 0, cnt2 = 0, cnt3 = 0;
    for (int base = 0; base < n; base += 64) {
        bool valid = base + lane < n;
        int pk = valid ? src[base + lane] : 0;
        int grp = (pk >> 20) & 3;
        cnt0 += (int)__popcll(__ballot(valid && grp == 0));
        cnt1 += (int)__popcll(__ballot(valid && grp == 1));
        cnt2 += (int)__popcll(__ballot(valid && grp == 2));
        cnt3 += (int)__popcll(__ballot(valid && grp == 3));
    }
    int s1 = cnt0, s2 = cnt0 + cnt1, s3 = cnt0 + cnt1 + cnt2;
    if (lane == 0) goff[bucket] = make_int4(0, s1, s2, s3);

    int c0 = 0, c1 = s1, c2 = s2, c3 = s3;
    for (int base = 0; base < n; base += 64) {
        bool valid = base + lane < n;
        int pk = valid ? src[base + lane] : 0;
        int grp = (pk >> 20) & 3;
        unsigned long long m0 = __ballot(valid && grp == 0);
        unsigned long long m1 = __ballot(valid && grp == 1);
        unsigned long long m2 = __ballot(valid && grp == 2);
        unsigned long long m3 = __ballot(valid && grp == 3);
        if (valid) {
            int p;
            if      (grp == 0) p = c0 + (int)__popcll(m0 & lmask);
            else if (grp == 1) p = c1 + (int)__popcll(m1 & lmask);
            else if (grp == 2) p = c2 + (int)__popcll(m2 & lmask);
            else               p = c3 + (int)__popcll(m3 & lmask);
            dst[p] = pk;
        }
        c0 += (int)__popcll(m0); c1 += (int)__popcll(m1);
        c2 += (int)__popcll(m2); c3 += (int)__popcll(m3);
    }
}

// KDEN: denominator table (fp32 exact g). Unchanged.
__global__ __launch_bounds__(256) void kden(
    const int* __restrict__ posv, const int* __restrict__ posh,
    const float* __restrict__ G2f, float* __restrict__ invden, int b0)
{
    int b   = b0 + (blockIdx.x >> 3);
    int phg = blockIdx.x & 7;
    int tid = threadIdx.x;

    __shared__ int   hist[64][64];
    __shared__ float g2s[128];
    __shared__ float tmp[64][8];

#pragma unroll
    for (int k = 0; k < 16; k++) ((int*)hist)[tid + (k << 8)] = 0;
    if (tid < 128) g2s[tid] = G2f[tid];
    __syncthreads();
#pragma unroll
    for (int k = 0; k < 8; k++) {
        int t = (k << 8) + tid;
        atomicAdd(&hist[posv[b * NT + t]][posh[b * NT + t]], 1);
    }
    __syncthreads();
#pragma unroll
    for (int c = 0; c < 2; c++) {
        int cell = (c << 8) + tid;
        int j    = cell >> 3;
        int phl  = cell & 7;
        int ph   = (phg << 3) + phl;
        float s = 0.f;
        for (int k = 0; k < 64; k++)
            s += (float)hist[j][k] * g2s[63 + k - ph];
        tmp[j][phl] = s;
    }
    __syncthreads();
#pragma unroll
    for (int c = 0; c < 2; c++) {
        int cell = (c << 8) + tid;
        int pv   = cell >> 3;
        int phl  = cell & 7;
        int ph   = (phg << 3) + phl;
        float s = 0.f;
        for (int j = 0; j < 64; j++)
            s += g2s[63 + j - pv] * tmp[j][phl];
        invden[(b * 64 + pv) * 64 + ph] = 1.0f / s;
    }
}

// B-fragment load: 8 bf16 at k = ks*32 + {4g..4g+3, 16+4g..16+4g+3}, row n.
__device__ __forceinline__ short8 ldsBfrag(const ushort_t* rowp, int ks, int g4) {
    const ushort_t* p = rowp + (ks << 5) + g4;
    uint2 lo = *(const uint2*)(p);
    uint2 hi = *(const uint2*)(p + 16);
    uint4 pk; pk.x = lo.x; pk.y = lo.y; pk.z = hi.x; pk.w = hi.y;
    return __builtin_bit_cast(short8, pk);
}

// K2: h-conv via MFMA — round-14 latency fixes.
//   Phase A: ONE meta VMEM per 64-token window (pkv = toks[win+lane]),
//     then v_readlane per token (uniform idx -> SGPR, no VMEM chain);
//     8 independent x-gathers in flight per sub-batch. Kills the
//     toks->readfirstlane->x serial round trips (the 60-70us floor of
//     rounds 8-13: all pipes <20% busy).
//   Phase B: MFMA as round 13, but accumulators parked in S16 LDS and
//     stored fully coalesced (128B rows) instead of 16x fragmented
//     4x32B stores per wave.
__global__ __launch_bounds__(256) void k2_convh(
    const float* __restrict__ x,
    const int* __restrict__ tokv2, const int* __restrict__ cntv,
    const int4* __restrict__ goff,
    const ushort_t* __restrict__ AfH, const ushort_t* __restrict__ AfL,
    ushort_t* __restrict__ B1, int b0)
{
    int pv   = blockIdx.x & 63;
    int dc   = (blockIdx.x >> 6) & 15;
    int b    = b0 + (blockIdx.x >> 10);
    int tid  = threadIdx.x;
    int lane = tid & 63;
    int w    = tid >> 6;
    int d0   = dc << 6;

    __shared__ float    S[64][65];     // S[d][ph] fp32 accum
    __shared__ ushort_t S16[64][68];   // bf16 operand; reused for output

#pragma unroll
    for (int k = 0; k < 17; k++) {
        int idx = (k << 8) + tid;
        if (idx < 64 * 65) ((float*)S)[idx] = 0.f;
    }
    __syncthreads();

    int bucket = (b << 6) + pv;
    int n = cntv[bucket];
    const int* toks = tokv2 + (size_t)bucket * CAP;
    const float* xb = x + (((size_t)b * NT) << 10) + d0 + lane;

    int4 go = goff[bucket];
    int gs = (w == 0) ? go.x : (w == 1) ? go.y : (w == 2) ? go.z : go.w;
    int ge = (w == 3) ? n   : (w == 0) ? go.y : (w == 1) ? go.z : go.w;

    // Phase A: windowed meta + readlane extraction + batched gathers.
    for (int win = gs; win < ge; win += 64) {
        int wn  = ge - win; if (wn > 64) wn = 64;      // uniform per wave
        int pkv = toks[win + lane];                    // 1 VMEM: 64 metas
        for (int i = 0; i < wn; i += 8) {
            int m = wn - i; if (m > 8) m = 8;          // uniform
            int pk[8]; float xv[8];
#pragma unroll
            for (int j = 0; j < 8; j++)
                pk[j] = __builtin_amdgcn_readlane(pkv, i + j);   // SGPR
#pragma unroll
            for (int j = 0; j < 8; j++)
                if (j < m) xv[j] = xb[(size_t)(pk[j] & 0xffff) << 10];
#pragma unroll
            for (int j = 0; j < 8; j++)
                if (j < m) S[lane][pk[j] >> 16] += xv[j];
        }
    }
    __syncthreads();

    // Convert S -> bf16 operand tile.
    {
        int r  = tid & 63;
        int c0 = (tid >> 6) << 4;
#pragma unroll
        for (int c = 0; c < 16; c++)
            S16[r][c0 + c] = f2bf(S[r][c0 + c]);
    }
    __syncthreads();

    // MFMA: Y[q][d] = (Ghi + Glo) . S16
    short8 ahi[2], alo[2];
#pragma unroll
    for (int ks = 0; ks < 2; ks++) {
        int idx = ((((w << 1) + ks) << 6) + lane) << 3;
        ahi[ks] = *(const short8*)(AfH + idx);
        alo[ks] = *(const short8*)(AfL + idx);
    }
    int g4 = (lane >> 4) << 2;
    int qbase = (w << 4) + g4;

    f32x4 accs[4];
#pragma unroll
    for (int nt = 0; nt < 4; nt++) {
        const ushort_t* rowp = &S16[(nt << 4) + (lane & 15)][0];
        f32x4 acc = {0.f, 0.f, 0.f, 0.f};
#pragma unroll
        for (int ks = 0; ks < 2; ks++) {
            short8 bf = ldsBfrag(rowp, ks, g4);
            acc = __builtin_amdgcn_mfma_f32_16x16x32_bf16(ahi[ks], bf, acc, 0, 0, 0);
            acc = __builtin_amdgcn_mfma_f32_16x16x32_bf16(alo[ks], bf, acc, 0, 0, 0);
        }
        accs[nt] = acc;
    }
    __syncthreads();                   // all S16 B-fragment reads done

    // Park results in S16 (rows=q, cols=d_local), then coalesced store.
#pragma unroll
    for (int nt = 0; nt < 4; nt++)
#pragma unroll
        for (int reg = 0; reg < 4; reg++)
            S16[qbase + reg][(nt << 4) + (lane & 15)] = f2bf(accs[nt][reg]);
    __syncthreads();

    ushort_t* B1p = B1 + (((size_t)(b - b0)) << 22) + (((size_t)pv) << 10) + d0;
#pragma unroll
    for (int pass = 0; pass < 2; pass++) {
        int row = (pass << 5) + (tid >> 3);      // 32 rows per pass
        int col = (tid & 7) << 3;                // 8 ushorts per thread
        uint4 v = *(const uint4*)(&S16[row][col]);
        *reinterpret_cast<uint4*>(B1p + ((size_t)row << 16) + col) = v;
    }
}

// K3: v-conv via MFMA + token scatter (unchanged from round 13 — ~15us).
__global__ __launch_bounds__(256) void k3_convv(
    const int* __restrict__ tokh, const int* __restrict__ cnth,
    const ushort_t* __restrict__ AfH, const ushort_t* __restrict__ AfL,
    const ushort_t* __restrict__ B1, const float* __restrict__ invden,
    float* __restrict__ out, int b0)
{
    int ph   = blockIdx.x & 63;
    int dc   = (blockIdx.x >> 6) & 15;
    int b    = b0 + (blockIdx.x >> 10);
    int tid  = threadIdx.x;
    int lane = tid & 63;
    int w    = tid >> 6;
    int d0   = dc << 6;

    int n = cnth[(b << 6) + ph];
    if (n == 0) return;               // uniform across block

    __shared__ ushort_t u16[64][68];  // u16[d][j]
    __shared__ float    y[64][65];

    const ushort_t* B1b = B1 + (((size_t)(b - b0)) << 22) + (((size_t)ph) << 16)
                        + d0 + lane;
#pragma unroll
    for (int it = 0; it < 16; it++) {
        int j = (w << 4) + it;
        u16[lane][j] = B1b[(size_t)j << 10];
    }
    __syncthreads();

    short8 ahi[2], alo[2];
#pragma unroll
    for (int ks = 0; ks < 2; ks++) {
        int idx = ((((w << 1) + ks) << 6) + lane) << 3;
        ahi[ks] = *(const short8*)(AfH + idx);
        alo[ks] = *(const short8*)(AfL + idx);
    }
    int g4 = (lane >> 4) << 2;
    int qbase = (w << 4) + g4;

#pragma unroll
    for (int nt = 0; nt < 4; nt++) {
        const ushort_t* rowp = &u16[(nt << 4) + (lane & 15)][0];
        f32x4 acc = {0.f, 0.f, 0.f, 0.f};
#pragma unroll
        for (int ks = 0; ks < 2; ks++) {
            short8 bf = ldsBfrag(rowp, ks, g4);
            acc = __builtin_amdgcn_mfma_f32_16x16x32_bf16(ahi[ks], bf, acc, 0, 0, 0);
            acc = __builtin_amdgcn_mfma_f32_16x16x32_bf16(alo[ks], bf, acc, 0, 0, 0);
        }
#pragma unroll
        for (int reg = 0; reg < 4; reg++)
            y[qbase + reg][(nt << 4) + (lane & 15)] = acc[reg];
    }
    __syncthreads();

    const int* toks = tokh + ((size_t)((b << 6) + ph)) * CAP;
    float* outb = out + (((size_t)b * NT) << 10) + d0 + lane;
    const float* ivb = invden + ((b << 6) << 6) + ph;

    int nch = (n + 3) >> 2;
    for (int c = w; c < nch; c += 4) {
        int i0 = c << 2;
        int4 M = *(const int4*)(toks + i0);   // safe past n: ws mapped
        int pk[4];
        pk[0] = __builtin_amdgcn_readfirstlane(M.x);
        pk[1] = __builtin_amdgcn_readfirstlane(M.y);
        pk[2] = __builtin_amdgcn_readfirstlane(M.z);
        pk[3] = __builtin_amdgcn_readfirstlane(M.w);
#pragma unroll
        for (int j = 0; j < 4; j++) {
            if (i0 + j < n) {
                int t   = pk[j] & 0xffff;
                int pvt = pk[j] >> 16;
                float iv = ivb[pvt << 6];
                outb[(size_t)t << 10] = y[pvt][lane] * iv;
            }
        }
    }
}

// Safety-net fallback (no workspace needed): direct O(T^2 * D) attention.
__global__ __launch_bounds__(256) void k_naive(
    const float* __restrict__ x, const int* __restrict__ posv,
    const int* __restrict__ posh, float* __restrict__ out)
{
    int t   = blockIdx.x & (NT - 1);
    int b   = blockIdx.x >> 11;
    int tid = threadIdx.x;

    __shared__ float s_w[NT];
    __shared__ float s_red[256];

    int pvt = posv[b * NT + t];
    int pht = posh[b * NT + t];

    float dsum = 0.0f;
    for (int s = tid; s < NT; s += 256) {
        int dv = pvt - posv[b * NT + s];
        int dh = pht - posh[b * NT + s];
        float w = expf(-(float)(dv * dv + dh * dh) * (1.0f / 512.0f));
        s_w[s] = w;
        dsum += w;
    }
    s_red[tid] = dsum;
    __syncthreads();
    for (int off = 128; off > 0; off >>= 1) {
        if (tid < off) s_red[tid] += s_red[tid + off];
        __syncthreads();
    }
    float inv = 1.0f / s_red[0];

    float a0 = 0.f, a1 = 0.f, a2 = 0.f, a3 = 0.f;
    for (int s = 0; s < NT; s++) {
        float w = s_w[s];
        const float* xr = x + (((size_t)(b * NT + s)) << 10);
        a0 = fmaf(w, xr[tid + 0],   a0);
        a1 = fmaf(w, xr[tid + 256], a1);
        a2 = fmaf(w, xr[tid + 512], a2);
        a3 = fmaf(w, xr[tid + 768], a3);
    }
    size_t ob = (((size_t)(b * NT + t)) << 10) + tid;
    out[ob + 0]   = a0 * inv;
    out[ob + 256] = a1 * inv;
    out[ob + 512] = a2 * inv;
    out[ob + 768] = a3 * inv;
}

extern "C" void kernel_launch(void* const* d_in, const int* in_sizes, int n_in,
                              void* d_out, int out_size, void* d_ws, size_t ws_size,
                              hipStream_t stream) {
    const float* x    = (const float*)d_in[0];
    const int*   posv = (const int*)d_in[1];
    const int*   posh = (const int*)d_in[2];
    float*       out  = (float*)d_out;

    char* ws = (char*)d_ws;
    float*    gbase  = (float*)ws;
    float*    G2f    = (float*)(ws + OFF_G2);
    ushort_t* AfH    = (ushort_t*)(ws + OFF_AFH);
    ushort_t* AfL    = (ushort_t*)(ws + OFF_AFL);
    int*      cntv   = (int*)(ws + OFF_CNTV);
    int*      cnth   = (int*)(ws + OFF_CNTH);
    float*    invden = (float*)(ws + OFF_INVDEN);
    int4*     goff   = (int4*)(ws + OFF_GOFF);
    int*      tokv   = (int*)(ws + OFF_TOKV);
    int*      tokh   = (int*)(ws + OFF_TOKH);
    int*      tokv2  = (int*)(ws + OFF_TOKV2);
    ushort_t* B1     = (ushort_t*)(ws + OFF_B1);

    const size_t needFull = (size_t)OFF_B1 + (size_t)NB * B1_SLAB;   // ~80 MB
    const size_t needLoop = (size_t)OFF_B1 + B1_SLAB;                // ~21 MB

    if (ws_size >= needFull) {
        k1_bucket<<<NB * 32, 256, 0, stream>>>(posv, posh, tokv, tokh, cntv, cnth,
                                               gbase, AfH, AfL);
        k1b_group<<<NB * 16, 256, 0, stream>>>(tokv, cntv, tokv2, goff);
        kden<<<NB * 8, 256, 0, stream>>>(posv, posh, G2f, invden, 0);
        k2_convh<<<NB * 1024, 256, 0, stream>>>(x, tokv2, cntv, goff, AfH, AfL, B1, 0);
        k3_convv<<<NB * 1024, 256, 0, stream>>>(tokh, cnth, AfH, AfL, B1, invden, out, 0);
    } else if (ws_size >= needLoop) {
        k1_bucket<<<NB * 32, 256, 0, stream>>>(posv, posh, tokv, tokh, cntv, cnth,
                                               gbase, AfH, AfL);
        k1b_group<<<NB * 16, 256, 0, stream>>>(tokv, cntv, tokv2, goff);
        for (int b = 0; b < NB; b++) {
            kden<<<8, 256, 0, stream>>>(posv, posh, G2f, invden, b);
            k2_convh<<<1024, 256, 0, stream>>>(x, tokv2, cntv, goff, AfH, AfL, B1, b);
            k3_convv<<<1024, 256, 0, stream>>>(tokh, cnth, AfH, AfL, B1, invden, out, b);
        }
    } else {
        k_naive<<<NB * NT, 256, 0, stream>>>(x, posv, posh, out);
    }
}

// Round 15
// 78.199 us; speedup vs baseline: 1.9437x; 1.0367x over previous
//
#include <hip/hip_runtime.h>
#include <hip/hip_bf16.h>

// Problem constants (fixed by setup_inputs): B=8, T=2048, D=1024, positions in [0,64).
#define NB 8
#define NT 2048
#define ND 1024
#define CAP 2048

typedef unsigned short ushort_t;
using short8 = __attribute__((ext_vector_type(8))) short;   // 8 bf16 (4 VGPR)
using f32x4  = __attribute__((ext_vector_type(4))) float;   // MFMA accum

__device__ __forceinline__ ushort_t f2bf(float f) {
    __hip_bfloat16 h = __float2bfloat16(f);
    return *reinterpret_cast<ushort_t*>(&h);
}
__device__ __forceinline__ float bf2f(ushort_t u) {
    unsigned int v = ((unsigned int)u) << 16;
    return __int_as_float((int)v);
}

// MFMA operand K-slot mapping for 16x16x32 bf16: k(g,i) = (i>>2)*16+4g+(i&3),
// g = lane>>4. Consistent on A-table (k1) and B-reads (k2/k3) -> any
// permutation error cancels over the reduction axis. C/D: col=lane&15,
// row=4*(lane>>4)+reg [HW-verified]. (Validated: rounds 13/14 absmax.)

// ---------------------------------------------------------------------------
// Workspace layout (byte offsets):
//   pad     : zeros (legacy)                                        @ 0
//   G2f     : 128 fp32  g(k-63), valid k in [0,126]                 @ 256
//   AfragHi : 4*2*64*8 bf16  A-fragment table, hi part              @ 768
//   AfragLo : same, lo part (g - hi)                                @ 8960
//   cntv    : NB*64 int                                             @ 17152
//   cnth    : NB*64 int                                             @ 19200
//   invden  : NB*64*64 fp32                                         @ 21248
//   goff    : NB*64 int4  per-bucket ph-group starts                @ 152320
//   tokv    : NB*64*CAP int  (t | posh<<16) by posv                 @ 160512
//   tokh    : NB*64*CAP int  (t | posv<<16) by posh                 @ 4354816
//   tokv2   : tokv regrouped by ph>>4                               @ 8549120
//   B1      : NB*64*64*1024 bf16  [b][q][pv][d]                     @ 12743424
// ---------------------------------------------------------------------------
#define OFF_G2     256
#define OFF_AFH    768
#define OFF_AFL    8960
#define OFF_CNTV   17152
#define OFF_CNTH   19200
#define OFF_INVDEN 21248
#define OFF_GOFF   152320
#define OFF_TOKV   160512
#define OFF_TOKH   4354816
#define OFF_TOKV2  8549120
#define OFF_B1     12743424
#define B1_SLAB    ((size_t)64 * 64 * 1024 * 2)   // 8 MB per batch (bf16)

// K1: deterministic CSR bucket lists via wave ballot compaction. Block 0
// also builds the fp32 g table AND the MFMA A-fragment tables (hi/lo bf16).
__global__ __launch_bounds__(256) void k1_bucket(
    const int* __restrict__ posv, const int* __restrict__ posh,
    int* __restrict__ tokv, int* __restrict__ tokh,
    int* __restrict__ cntv, int* __restrict__ cnth,
    float* __restrict__ gbase, ushort_t* __restrict__ AfH,
    ushort_t* __restrict__ AfL)
{
    int b    = blockIdx.x >> 5;
    int blk  = blockIdx.x & 31;
    int wave = threadIdx.x >> 6;
    int lane = threadIdx.x & 63;

    if (blockIdx.x == 0) {
        if (threadIdx.x < 192) {
            int k = (int)threadIdx.x - 64;
            float v = 0.0f;
            if (k >= 0 && k < 127) {
                int r = k - 63;
                v = expf(-(float)(r * r) * (1.0f / 512.0f));
            }
            gbase[threadIdx.x] = v;
        }
#pragma unroll
        for (int p = 0; p < 16; p++) {
            int pos = (p << 8) + (int)threadIdx.x;   // 0..4095
            int i   = pos & 7;
            int ln  = (pos >> 3) & 63;
            int ks  = (pos >> 9) & 1;
            int w   = pos >> 10;
            int q   = (w << 4) + (ln & 15);
            int k   = (ks << 5) + ((i >> 2) << 4) + ((ln >> 4) << 2) + (i & 3);
            int dlt = q - k;
            float g = expf(-(float)(dlt * dlt) * (1.0f / 512.0f));
            ushort_t hi = f2bf(g);
            AfH[pos] = hi;
            AfL[pos] = f2bf(g - bf2f(hi));
        }
    }

    int task   = blk * 4 + wave;
    int bucket = task & 63;
    int use_ph = task >> 6;
    const int* pos  = use_ph ? posh : posv;
    const int* opos = use_ph ? posv : posh;
    int* tok = (use_ph ? tokh : tokv) + ((size_t)(b * 64 + bucket)) * CAP;
    int* cnt = use_ph ? cnth : cntv;

    int vals[32];
#pragma unroll
    for (int k = 0; k < 32; k++) vals[k] = pos[b * NT + k * 64 + lane];

    unsigned long long lmask = (1ull << lane) - 1ull;
    int cursor = 0;
#pragma unroll 4
    for (int k = 0; k < 32; k++) {
        bool hit = (vals[k] == bucket);
        unsigned long long m = __ballot(hit);
        if (hit) {
            int t = k * 64 + lane;
            tok[cursor + __popcll(m & lmask)] = t | (opos[b * NT + t] << 16);
        }
        cursor += (int)__popcll(m);
    }
    if (lane == 0) cnt[b * 64 + bucket] = cursor;
}

// K1b: regroup each (b,pv) bucket by ph>>4 into 4 wave-groups (stable,
// deterministic). One bucket per wave.
__global__ __launch_bounds__(256) void k1b_group(
    const int* __restrict__ tokv, const int* __restrict__ cntv,
    int* __restrict__ tokv2, int4* __restrict__ goff)
{
    int bucket = blockIdx.x * 4 + (threadIdx.x >> 6);
    int lane   = threadIdx.x & 63;
    int n = cntv[bucket];
    const int* src = tokv + (size_t)bucket * CAP;
    int* dst = tokv2 + (size_t)bucket * CAP;
    unsigned long long lmask = (1ull << lane) - 1ull;

    int cnt0 = 0, cnt1 = 0, cnt2 = 0, cnt3 = 0;
    for (int base = 0; base < n; base += 64) {
        bool valid = base + lane < n;
        int pk = valid ? src[base + lane] : 0;
        int grp = (pk >> 20) & 3;
        cnt0 += (int)__popcll(__ballot(valid && grp == 0));
        cnt1 += (int)__popcll(__ballot(valid && grp == 1));
        cnt2 += (int)__popcll(__ballot(valid && grp == 2));
        cnt3 += (int)__popcll(__ballot(valid && grp == 3));
    }
    int s1 = cnt0, s2 = cnt0 + cnt1, s3 = cnt0 + cnt1 + cnt2;
    if (lane == 0) goff[bucket] = make_int4(0, s1, s2, s3);

    int c0 = 0, c1 = s1, c2 = s2, c3 = s3;
    for (int base = 0; base < n; base += 64) {
        bool valid = base + lane < n;
        int pk = valid ? src[base + lane] : 0;
        int grp = (pk >> 20) & 3;
        unsigned long long m0 = __ballot(valid && grp == 0);
        unsigned long long m1 = __ballot(valid && grp == 1);
        unsigned long long m2 = __ballot(valid && grp == 2);
        unsigned long long m3 = __ballot(valid && grp == 3);
        if (valid) {
            int p;
            if      (grp == 0) p = c0 + (int)__popcll(m0 & lmask);
            else if (grp == 1) p = c1 + (int)__popcll(m1 & lmask);
            else if (grp == 2) p = c2 + (int)__popcll(m2 & lmask);
            else               p = c3 + (int)__popcll(m3 & lmask);
            dst[p] = pk;
        }
        c0 += (int)__popcll(m0); c1 += (int)__popcll(m1);
        c2 += (int)__popcll(m2); c3 += (int)__popcll(m3);
    }
}

// KDEN: denominator table (fp32 exact g). Unchanged.
__global__ __launch_bounds__(256) void kden(
    const int* __restrict__ posv, const int* __restrict__ posh,
    const float* __restrict__ G2f, float* __restrict__ invden, int b0)
{
    int b   = b0 + (blockIdx.x >> 3);
    int phg = blockIdx.x & 7;
    int tid = threadIdx.x;

    __shared__ int   hist[64][64];
    __shared__ float g2s[128];
    __shared__ float tmp[64][8];

#pragma unroll
    for (int k = 0; k < 16; k++) ((int*)hist)[tid + (k << 8)] = 0;
    if (tid < 128) g2s[tid] = G2f[tid];
    __syncthreads();
#pragma unroll
    for (int k = 0; k < 8; k++) {
        int t = (k << 8) + tid;
        atomicAdd(&hist[posv[b * NT + t]][posh[b * NT + t]], 1);
    }
    __syncthreads();
#pragma unroll
    for (int c = 0; c < 2; c++) {
        int cell = (c << 8) + tid;
        int j    = cell >> 3;
        int phl  = cell & 7;
        int ph   = (phg << 3) + phl;
        float s = 0.f;
        for (int k = 0; k < 64; k++)
            s += (float)hist[j][k] * g2s[63 + k - ph];
        tmp[j][phl] = s;
    }
    __syncthreads();
#pragma unroll
    for (int c = 0; c < 2; c++) {
        int cell = (c << 8) + tid;
        int pv   = cell >> 3;
        int phl  = cell & 7;
        int ph   = (phg << 3) + phl;
        float s = 0.f;
        for (int j = 0; j < 64; j++)
            s += g2s[63 + j - pv] * tmp[j][phl];
        invden[(b * 64 + pv) * 64 + ph] = 1.0f / s;
    }
}

// B-fragment load: 8 bf16 at k = ks*32 + {4g..4g+3, 16+4g..16+4g+3}, row n.
__device__ __forceinline__ short8 ldsBfrag(const ushort_t* rowp, int ks, int g4) {
    const ushort_t* p = rowp + (ks << 5) + g4;
    uint2 lo = *(const uint2*)(p);
    uint2 hi = *(const uint2*)(p + 16);
    uint4 pk; pk.x = lo.x; pk.y = lo.y; pk.z = hi.x; pk.w = hi.y;
    return __builtin_bit_cast(short8, pk);
}

// K2: h-conv via MFMA — round-15 occupancy + prefetch fixes.
//   LDS: one 16.6KB union buffer (S fp32 / S16 bf16, barrier-disciplined
//     in-place convert) — was 25.6KB = 6 blocks/CU, now 9 (occ 49 -> ~75%).
//   Phase A: window-0 meta + first 8 x-gathers issued BEFORE the LDS zero
//     (the pre-barrier vmcnt drain completes them under the zero's shadow).
__global__ __launch_bounds__(256) void k2_convh(
    const float* __restrict__ x,
    const int* __restrict__ tokv2, const int* __restrict__ cntv,
    const int4* __restrict__ goff,
    const ushort_t* __restrict__ AfH, const ushort_t* __restrict__ AfL,
    ushort_t* __restrict__ B1, int b0)
{
    int pv   = blockIdx.x & 63;
    int dc   = (blockIdx.x >> 6) & 15;
    int b    = b0 + (blockIdx.x >> 10);
    int tid  = threadIdx.x;
    int lane = tid & 63;
    int w    = tid >> 6;
    int d0   = dc << 6;

    __shared__ float ldsf[64 * 65];               // 16640 B union buffer
    float    (*S)[65]   = (float(*)[65])ldsf;     // fp32 accum  S[d][ph]
    ushort_t (*S16)[68] = (ushort_t(*)[68])ldsf;  // bf16 operand / output

    int bucket = (b << 6) + pv;
    int n = cntv[bucket];
    const int* toks = tokv2 + (size_t)bucket * CAP;
    const float* xb = x + (((size_t)b * NT) << 10) + d0 + lane;

    int4 go = goff[bucket];
    int gs = (w == 0) ? go.x : (w == 1) ? go.y : (w == 2) ? go.z : go.w;
    int ge = (w == 3) ? n   : (w == 0) ? go.y : (w == 1) ? go.z : go.w;

    // --- prefetch window 0 (meta + first 8 gathers) before LDS zeroing ---
    int wn0 = ge - gs; if (wn0 < 0) wn0 = 0; if (wn0 > 64) wn0 = 64;
    int m0  = wn0 > 8 ? 8 : wn0;
    int pkv = (wn0 > 0) ? toks[gs + lane] : 0;
    int pk0[8]; float xv0[8];
#pragma unroll
    for (int j = 0; j < 8; j++) pk0[j] = __builtin_amdgcn_readlane(pkv, j);
#pragma unroll
    for (int j = 0; j < 8; j++)
        if (j < m0) xv0[j] = xb[(size_t)(pk0[j] & 0xffff) << 10];

    // zero S while the loads are in flight
#pragma unroll
    for (int k = 0; k < 17; k++) {
        int idx = (k << 8) + tid;
        if (idx < 64 * 65) ldsf[idx] = 0.f;
    }
    __syncthreads();

    // consume prefetched batch
#pragma unroll
    for (int j = 0; j < 8; j++)
        if (j < m0) S[lane][pk0[j] >> 16] += xv0[j];

    // rest of window 0
    for (int i = 8; i < wn0; i += 8) {
        int m = wn0 - i; if (m > 8) m = 8;
        int pk[8]; float xv[8];
#pragma unroll
        for (int j = 0; j < 8; j++) pk[j] = __builtin_amdgcn_readlane(pkv, i + j);
#pragma unroll
        for (int j = 0; j < 8; j++)
            if (j < m) xv[j] = xb[(size_t)(pk[j] & 0xffff) << 10];
#pragma unroll
        for (int j = 0; j < 8; j++)
            if (j < m) S[lane][pk[j] >> 16] += xv[j];
    }
    // windows 1.. (rare: wave-group >64 tokens)
    for (int win = gs + 64; win < ge; win += 64) {
        int wn = ge - win; if (wn > 64) wn = 64;
        int pkw = toks[win + lane];
        for (int i = 0; i < wn; i += 8) {
            int m = wn - i; if (m > 8) m = 8;
            int pk[8]; float xv[8];
#pragma unroll
            for (int j = 0; j < 8; j++) pk[j] = __builtin_amdgcn_readlane(pkw, i + j);
#pragma unroll
            for (int j = 0; j < 8; j++)
                if (j < m) xv[j] = xb[(size_t)(pk[j] & 0xffff) << 10];
#pragma unroll
            for (int j = 0; j < 8; j++)
                if (j < m) S[lane][pk[j] >> 16] += xv[j];
        }
    }
    __syncthreads();

    // in-place fp32 -> bf16 convert (read to regs, barrier, aliased write)
    {
        int r  = tid & 63;
        int c0 = (tid >> 6) << 4;
        float vals[16];
#pragma unroll
        for (int c = 0; c < 16; c++) vals[c] = S[r][c0 + c];
        __syncthreads();
#pragma unroll
        for (int c = 0; c < 16; c++) S16[r][c0 + c] = f2bf(vals[c]);
    }
    __syncthreads();

    // MFMA: Y[q][d] = (Ghi + Glo) . S16
    short8 ahi[2], alo[2];
#pragma unroll
    for (int ks = 0; ks < 2; ks++) {
        int idx = ((((w << 1) + ks) << 6) + lane) << 3;
        ahi[ks] = *(const short8*)(AfH + idx);
        alo[ks] = *(const short8*)(AfL + idx);
    }
    int g4 = (lane >> 4) << 2;
    int qbase = (w << 4) + g4;

    f32x4 accs[4];
#pragma unroll
    for (int nt = 0; nt < 4; nt++) {
        const ushort_t* rowp = &S16[(nt << 4) + (lane & 15)][0];
        f32x4 acc = {0.f, 0.f, 0.f, 0.f};
#pragma unroll
        for (int ks = 0; ks < 2; ks++) {
            short8 bf = ldsBfrag(rowp, ks, g4);
            acc = __builtin_amdgcn_mfma_f32_16x16x32_bf16(ahi[ks], bf, acc, 0, 0, 0);
            acc = __builtin_amdgcn_mfma_f32_16x16x32_bf16(alo[ks], bf, acc, 0, 0, 0);
        }
        accs[nt] = acc;
    }
    __syncthreads();                   // all S16 B-fragment reads done

    // Park results (rows=q, cols=d_local), then coalesced store.
#pragma unroll
    for (int nt = 0; nt < 4; nt++)
#pragma unroll
        for (int reg = 0; reg < 4; reg++)
            S16[qbase + reg][(nt << 4) + (lane & 15)] = f2bf(accs[nt][reg]);
    __syncthreads();

    ushort_t* B1p = B1 + (((size_t)(b - b0)) << 22) + (((size_t)pv) << 10) + d0;
#pragma unroll
    for (int pass = 0; pass < 2; pass++) {
        int row = (pass << 5) + (tid >> 3);      // 32 rows per pass
        int col = (tid & 7) << 3;                // 8 ushorts per thread
        uint4 v = *(const uint4*)(&S16[row][col]);
        *reinterpret_cast<uint4*>(B1p + ((size_t)row << 16) + col) = v;
    }
}

// K3: v-conv via MFMA + token scatter — round-15: LDS union (u16/y in one
// 16.6KB buffer, accs held in registers so no y-write aliases unread u16).
__global__ __launch_bounds__(256) void k3_convv(
    const int* __restrict__ tokh, const int* __restrict__ cnth,
    const ushort_t* __restrict__ AfH, const ushort_t* __restrict__ AfL,
    const ushort_t* __restrict__ B1, const float* __restrict__ invden,
    float* __restrict__ out, int b0)
{
    int ph   = blockIdx.x & 63;
    int dc   = (blockIdx.x >> 6) & 15;
    int b    = b0 + (blockIdx.x >> 10);
    int tid  = threadIdx.x;
    int lane = tid & 63;
    int w    = tid >> 6;
    int d0   = dc << 6;

    int n = cnth[(b << 6) + ph];
    if (n == 0) return;               // uniform across block

    __shared__ float ldsf[64 * 65];              // 16640 B union buffer
    ushort_t (*u16)[68] = (ushort_t(*)[68])ldsf; // staged B1 column
    float    (*y)[65]   = (float(*)[65])ldsf;    // conv output

    const ushort_t* B1b = B1 + (((size_t)(b - b0)) << 22) + (((size_t)ph) << 16)
                        + d0 + lane;
#pragma unroll
    for (int it = 0; it < 16; it++) {
        int j = (w << 4) + it;
        u16[lane][j] = B1b[(size_t)j << 10];
    }
    __syncthreads();

    short8 ahi[2], alo[2];
#pragma unroll
    for (int ks = 0; ks < 2; ks++) {
        int idx = ((((w << 1) + ks) << 6) + lane) << 3;
        ahi[ks] = *(const short8*)(AfH + idx);
        alo[ks] = *(const short8*)(AfL + idx);
    }
    int g4 = (lane >> 4) << 2;
    int qbase = (w << 4) + g4;

    f32x4 accs[4];
#pragma unroll
    for (int nt = 0; nt < 4; nt++) {
        const ushort_t* rowp = &u16[(nt << 4) + (lane & 15)][0];
        f32x4 acc = {0.f, 0.f, 0.f, 0.f};
#pragma unroll
        for (int ks = 0; ks < 2; ks++) {
            short8 bf = ldsBfrag(rowp, ks, g4);
            acc = __builtin_amdgcn_mfma_f32_16x16x32_bf16(ahi[ks], bf, acc, 0, 0, 0);
            acc = __builtin_amdgcn_mfma_f32_16x16x32_bf16(alo[ks], bf, acc, 0, 0, 0);
        }
        accs[nt] = acc;
    }
    __syncthreads();                   // all u16 reads done before y writes

#pragma unroll
    for (int nt = 0; nt < 4; nt++)
#pragma unroll
        for (int reg = 0; reg < 4; reg++)
            y[qbase + reg][(nt << 4) + (lane & 15)] = accs[nt][reg];
    __syncthreads();

    const int* toks = tokh + ((size_t)((b << 6) + ph)) * CAP;
    float* outb = out + (((size_t)b * NT) << 10) + d0 + lane;
    const float* ivb = invden + ((b << 6) << 6) + ph;

    int nch = (n + 3) >> 2;
    for (int c = w; c < nch; c += 4) {
        int i0 = c << 2;
        int4 M = *(const int4*)(toks + i0);   // safe past n: ws mapped
        int pk[4];
        pk[0] = __builtin_amdgcn_readfirstlane(M.x);
        pk[1] = __builtin_amdgcn_readfirstlane(M.y);
        pk[2] = __builtin_amdgcn_readfirstlane(M.z);
        pk[3] = __builtin_amdgcn_readfirstlane(M.w);
#pragma unroll
        for (int j = 0; j < 4; j++) {
            if (i0 + j < n) {
                int t   = pk[j] & 0xffff;
                int pvt = pk[j] >> 16;
                float iv = ivb[pvt << 6];
                outb[(size_t)t << 10] = y[pvt][lane] * iv;
            }
        }
    }
}

// Safety-net fallback (no workspace needed): direct O(T^2 * D) attention.
__global__ __launch_bounds__(256) void k_naive(
    const float* __restrict__ x, const int* __restrict__ posv,
    const int* __restrict__ posh, float* __restrict__ out)
{
    int t   = blockIdx.x & (NT - 1);
    int b   = blockIdx.x >> 11;
    int tid = threadIdx.x;

    __shared__ float s_w[NT];
    __shared__ float s_red[256];

    int pvt = posv[b * NT + t];
    int pht = posh[b * NT + t];

    float dsum = 0.0f;
    for (int s = tid; s < NT; s += 256) {
        int dv = pvt - posv[b * NT + s];
        int dh = pht - posh[b * NT + s];
        float w = expf(-(float)(dv * dv + dh * dh) * (1.0f / 512.0f));
        s_w[s] = w;
        dsum += w;
    }
    s_red[tid] = dsum;
    __syncthreads();
    for (int off = 128; off > 0; off >>= 1) {
        if (tid < off) s_red[tid] += s_red[tid + off];
        __syncthreads();
    }
    float inv = 1.0f / s_red[0];

    float a0 = 0.f, a1 = 0.f, a2 = 0.f, a3 = 0.f;
    for (int s = 0; s < NT; s++) {
        float w = s_w[s];
        const float* xr = x + (((size_t)(b * NT + s)) << 10);
        a0 = fmaf(w, xr[tid + 0],   a0);
        a1 = fmaf(w, xr[tid + 256], a1);
        a2 = fmaf(w, xr[tid + 512], a2);
        a3 = fmaf(w, xr[tid + 768], a3);
    }
    size_t ob = (((size_t)(b * NT + t)) << 10) + tid;
    out[ob + 0]   = a0 * inv;
    out[ob + 256] = a1 * inv;
    out[ob + 512] = a2 * inv;
    out[ob + 768] = a3 * inv;
}

extern "C" void kernel_launch(void* const* d_in, const int* in_sizes, int n_in,
                              void* d_out, int out_size, void* d_ws, size_t ws_size,
                              hipStream_t stream) {
    const float* x    = (const float*)d_in[0];
    const int*   posv = (const int*)d_in[1];
    const int*   posh = (const int*)d_in[2];
    float*       out  = (float*)d_out;

    char* ws = (char*)d_ws;
    float*    gbase  = (float*)ws;
    float*    G2f    = (float*)(ws + OFF_G2);
    ushort_t* AfH    = (ushort_t*)(ws + OFF_AFH);
    ushort_t* AfL    = (ushort_t*)(ws + OFF_AFL);
    int*      cntv   = (int*)(ws + OFF_CNTV);
    int*      cnth   = (int*)(ws + OFF_CNTH);
    float*    invden = (float*)(ws + OFF_INVDEN);
    int4*     goff   = (int4*)(ws + OFF_GOFF);
    int*      tokv   = (int*)(ws + OFF_TOKV);
    int*      tokh   = (int*)(ws + OFF_TOKH);
    int*      tokv2  = (int*)(ws + OFF_TOKV2);
    ushort_t* B1     = (ushort_t*)(ws + OFF_B1);

    const size_t needFull = (size_t)OFF_B1 + (size_t)NB * B1_SLAB;   // ~80 MB
    const size_t needLoop = (size_t)OFF_B1 + B1_SLAB;                // ~21 MB

    if (ws_size >= needFull) {
        k1_bucket<<<NB * 32, 256, 0, stream>>>(posv, posh, tokv, tokh, cntv, cnth,
                                               gbase, AfH, AfL);
        k1b_group<<<NB * 16, 256, 0, stream>>>(tokv, cntv, tokv2, goff);
        kden<<<NB * 8, 256, 0, stream>>>(posv, posh, G2f, invden, 0);
        k2_convh<<<NB * 1024, 256, 0, stream>>>(x, tokv2, cntv, goff, AfH, AfL, B1, 0);
        k3_convv<<<NB * 1024, 256, 0, stream>>>(tokh, cnth, AfH, AfL, B1, invden, out, 0);
    } else if (ws_size >= needLoop) {
        k1_bucket<<<NB * 32, 256, 0, stream>>>(posv, posh, tokv, tokh, cntv, cnth,
                                               gbase, AfH, AfL);
        k1b_group<<<NB * 16, 256, 0, stream>>>(tokv, cntv, tokv2, goff);
        for (int b = 0; b < NB; b++) {
            kden<<<8, 256, 0, stream>>>(posv, posh, G2f, invden, b);
            k2_convh<<<1024, 256, 0, stream>>>(x, tokv2, cntv, goff, AfH, AfL, B1, b);
            k3_convv<<<1024, 256, 0, stream>>>(tokh, cnth, AfH, AfL, B1, invden, out, b);
        }
    } else {
        k_naive<<<NB * NT, 256, 0, stream>>>(x, posv, posh, out);
    }
}

// Round 16
// 75.879 us; speedup vs baseline: 2.0031x; 1.0306x over previous
//
#include <hip/hip_runtime.h>
#include <hip/hip_bf16.h>

// Problem constants (fixed by setup_inputs): B=8, T=2048, D=1024, positions in [0,64).
#define NB 8
#define NT 2048
#define ND 1024
#define CAP 2048

typedef unsigned short ushort_t;
using short8 = __attribute__((ext_vector_type(8))) short;   // 8 bf16 (4 VGPR)
using f32x4  = __attribute__((ext_vector_type(4))) float;   // MFMA accum

__device__ __forceinline__ ushort_t f2bf(float f) {
    __hip_bfloat16 h = __float2bfloat16(f);
    return *reinterpret_cast<ushort_t*>(&h);
}
__device__ __forceinline__ float bf2f(ushort_t u) {
    unsigned int v = ((unsigned int)u) << 16;
    return __int_as_float((int)v);
}

// MFMA operand K-slot mapping for 16x16x32 bf16: k(g,i) = (i>>2)*16+4g+(i&3),
// g = lane>>4. Consistent on A-table (k1) and B-reads (k2/k3) -> any
// permutation error cancels over the reduction axis. C/D: col=lane&15,
// row=4*(lane>>4)+reg [HW-verified]. (Validated: rounds 13-15 absmax.)

// ---------------------------------------------------------------------------
// Workspace layout (byte offsets): (unchanged from round 15)
// ---------------------------------------------------------------------------
#define OFF_G2     256
#define OFF_AFH    768
#define OFF_AFL    8960
#define OFF_CNTV   17152
#define OFF_CNTH   19200
#define OFF_INVDEN 21248
#define OFF_GOFF   152320
#define OFF_TOKV   160512
#define OFF_TOKH   4354816
#define OFF_TOKV2  8549120
#define OFF_B1     12743424
#define B1_SLAB    ((size_t)64 * 64 * 1024 * 2)   // 8 MB per batch (bf16)

// Shared kden body: denominator table via LDS-atomic histogram (deterministic
// values — integer adds) + two 64x64 mini-matmuls. g table computed LOCALLY
// (no dependence on k1 block 0's G2f write -> safe to run merged with k1).
__device__ __forceinline__ void kden_body(
    int kb, const int* __restrict__ posv, const int* __restrict__ posh,
    float* __restrict__ invden, int b0)
{
    int b   = b0 + (kb >> 3);
    int phg = kb & 7;
    int tid = threadIdx.x;

    __shared__ int   hist[64][64];
    __shared__ float g2s[128];
    __shared__ float tmp[64][8];

#pragma unroll
    for (int k = 0; k < 16; k++) ((int*)hist)[tid + (k << 8)] = 0;
    if (tid < 128) {
        int k = tid, r = k - 63;
        g2s[tid] = (k < 127) ? expf(-(float)(r * r) * (1.0f / 512.0f)) : 0.0f;
    }
    __syncthreads();
#pragma unroll
    for (int k = 0; k < 8; k++) {
        int t = (k << 8) + tid;
        atomicAdd(&hist[posv[b * NT + t]][posh[b * NT + t]], 1);
    }
    __syncthreads();
#pragma unroll
    for (int c = 0; c < 2; c++) {
        int cell = (c << 8) + tid;
        int j    = cell >> 3;
        int phl  = cell & 7;
        int ph   = (phg << 3) + phl;
        float s = 0.f;
        for (int k = 0; k < 64; k++)
            s += (float)hist[j][k] * g2s[63 + k - ph];
        tmp[j][phl] = s;
    }
    __syncthreads();
#pragma unroll
    for (int c = 0; c < 2; c++) {
        int cell = (c << 8) + tid;
        int pv   = cell >> 3;
        int phl  = cell & 7;
        int ph   = (phg << 3) + phl;
        float s = 0.f;
        for (int j = 0; j < 64; j++)
            s += g2s[63 + j - pv] * tmp[j][phl];
        invden[(b * 64 + pv) * 64 + ph] = 1.0f / s;
    }
}

// K1: deterministic CSR bucket lists via wave ballot compaction. Block 0
// builds the g table + MFMA A-fragment tables. Blocks >= nbkt run the
// kden body (independent of k1's outputs) — saves one serial dispatch.
__global__ __launch_bounds__(256) void k1_bucket(
    const int* __restrict__ posv, const int* __restrict__ posh,
    int* __restrict__ tokv, int* __restrict__ tokh,
    int* __restrict__ cntv, int* __restrict__ cnth,
    float* __restrict__ gbase, ushort_t* __restrict__ AfH,
    ushort_t* __restrict__ AfL, float* __restrict__ invden, int nbkt)
{
    if ((int)blockIdx.x >= nbkt) {            // fused kden blocks
        kden_body((int)blockIdx.x - nbkt, posv, posh, invden, 0);
        return;
    }

    int b    = blockIdx.x >> 5;
    int blk  = blockIdx.x & 31;
    int wave = threadIdx.x >> 6;
    int lane = threadIdx.x & 63;

    if (blockIdx.x == 0) {
        if (threadIdx.x < 192) {
            int k = (int)threadIdx.x - 64;
            float v = 0.0f;
            if (k >= 0 && k < 127) {
                int r = k - 63;
                v = expf(-(float)(r * r) * (1.0f / 512.0f));
            }
            gbase[threadIdx.x] = v;
        }
#pragma unroll
        for (int p = 0; p < 16; p++) {
            int pos = (p << 8) + (int)threadIdx.x;   // 0..4095
            int i   = pos & 7;
            int ln  = (pos >> 3) & 63;
            int ks  = (pos >> 9) & 1;
            int w   = pos >> 10;
            int q   = (w << 4) + (ln & 15);
            int k   = (ks << 5) + ((i >> 2) << 4) + ((ln >> 4) << 2) + (i & 3);
            int dlt = q - k;
            float g = expf(-(float)(dlt * dlt) * (1.0f / 512.0f));
            ushort_t hi = f2bf(g);
            AfH[pos] = hi;
            AfL[pos] = f2bf(g - bf2f(hi));
        }
    }

    int task   = blk * 4 + wave;
    int bucket = task & 63;
    int use_ph = task >> 6;
    const int* pos  = use_ph ? posh : posv;
    const int* opos = use_ph ? posv : posh;
    int* tok = (use_ph ? tokh : tokv) + ((size_t)(b * 64 + bucket)) * CAP;
    int* cnt = use_ph ? cnth : cntv;

    int vals[32];
#pragma unroll
    for (int k = 0; k < 32; k++) vals[k] = pos[b * NT + k * 64 + lane];

    unsigned long long lmask = (1ull << lane) - 1ull;
    int cursor = 0;
#pragma unroll 4
    for (int k = 0; k < 32; k++) {
        bool hit = (vals[k] == bucket);
        unsigned long long m = __ballot(hit);
        if (hit) {
            int t = k * 64 + lane;
            tok[cursor + __popcll(m & lmask)] = t | (opos[b * NT + t] << 16);
        }
        cursor += (int)__popcll(m);
    }
    if (lane == 0) cnt[b * 64 + bucket] = cursor;
}

// Standalone kden (loop path only).
__global__ __launch_bounds__(256) void kden(
    const int* __restrict__ posv, const int* __restrict__ posh,
    float* __restrict__ invden, int b0)
{
    kden_body((int)blockIdx.x, posv, posh, invden, b0);
}

// K1b: regroup each (b,pv) bucket by ph>>4 into 4 wave-groups (stable,
// deterministic). One bucket per wave.
__global__ __launch_bounds__(256) void k1b_group(
    const int* __restrict__ tokv, const int* __restrict__ cntv,
    int* __restrict__ tokv2, int4* __restrict__ goff)
{
    int bucket = blockIdx.x * 4 + (threadIdx.x >> 6);
    int lane   = threadIdx.x & 63;
    int n = cntv[bucket];
    const int* src = tokv + (size_t)bucket * CAP;
    int* dst = tokv2 + (size_t)bucket * CAP;
    unsigned long long lmask = (1ull << lane) - 1ull;

    int cnt0 = 0, cnt1 = 0, cnt2 = 0, cnt3 = 0;
    for (int base = 0; base < n; base += 64) {
        bool valid = base + lane < n;
        int pk = valid ? src[base + lane] : 0;
        int grp = (pk >> 20) & 3;
        cnt0 += (int)__popcll(__ballot(valid && grp == 0));
        cnt1 += (int)__popcll(__ballot(valid && grp == 1));
        cnt2 += (int)__popcll(__ballot(valid && grp == 2));
        cnt3 += (int)__popcll(__ballot(valid && grp == 3));
    }
    int s1 = cnt0, s2 = cnt0 + cnt1, s3 = cnt0 + cnt1 + cnt2;
    if (lane == 0) goff[bucket] = make_int4(0, s1, s2, s3);

    int c0 = 0, c1 = s1, c2 = s2, c3 = s3;
    for (int base = 0; base < n; base += 64) {
        bool valid = base + lane < n;
        int pk = valid ? src[base + lane] : 0;
        int grp = (pk >> 20) & 3;
        unsigned long long m0 = __ballot(valid && grp == 0);
        unsigned long long m1 = __ballot(valid && grp == 1);
        unsigned long long m2 = __ballot(valid && grp == 2);
        unsigned long long m3 = __ballot(valid && grp == 3);
        if (valid) {
            int p;
            if      (grp == 0) p = c0 + (int)__popcll(m0 & lmask);
            else if (grp == 1) p = c1 + (int)__popcll(m1 & lmask);
            else if (grp == 2) p = c2 + (int)__popcll(m2 & lmask);
            else               p = c3 + (int)__popcll(m3 & lmask);
            dst[p] = pk;
        }
        c0 += (int)__popcll(m0); c1 += (int)__popcll(m1);
        c2 += (int)__popcll(m2); c3 += (int)__popcll(m3);
    }
}

// B-fragment load: 8 bf16 at k = ks*32 + {4g..4g+3, 16+4g..16+4g+3}, row n.
__device__ __forceinline__ short8 ldsBfrag(const ushort_t* rowp, int ks, int g4) {
    const ushort_t* p = rowp + (ks << 5) + g4;
    uint2 lo = *(const uint2*)(p);
    uint2 hi = *(const uint2*)(p + 16);
    uint4 pk; pk.x = lo.x; pk.y = lo.y; pk.z = hi.x; pk.w = hi.y;
    return __builtin_bit_cast(short8, pk);
}

// K2: h-conv via MFMA — round-16: REGISTER accumulation.
// k1b's grouping means wave w only sees ph in [16w,16w+16) -> per-lane
// acc[16] registers replace the fp32 LDS S entirely (one-hot select on a
// scalar phl; all indices compile-time). Deletes: zero loop, LDS RMW pass,
// fp32->bf16 convert phase, 3 barriers. LDS 16.9 -> 8.7 KB.
// acc[16]+xv[8] ~ 45 VGPR — a live-set the allocator has held since round 8;
// (256,4) caps at 128 VGPR (>= need) while guaranteeing 4 waves/SIMD.
__global__ __launch_bounds__(256, 4) void k2_convh(
    const float* __restrict__ x,
    const int* __restrict__ tokv2, const int* __restrict__ cntv,
    const int4* __restrict__ goff,
    const ushort_t* __restrict__ AfH, const ushort_t* __restrict__ AfL,
    ushort_t* __restrict__ B1, int b0)
{
    int pv   = blockIdx.x & 63;
    int dc   = (blockIdx.x >> 6) & 15;
    int b    = b0 + (blockIdx.x >> 10);
    int tid  = threadIdx.x;
    int lane = tid & 63;
    int w    = tid >> 6;
    int d0   = dc << 6;

    __shared__ ushort_t S16[64][68];   // 8.7 KB: bf16 operand, then output park

    int bucket = (b << 6) + pv;
    int n = cntv[bucket];
    const int* toks = tokv2 + (size_t)bucket * CAP;
    const float* xb = x + (((size_t)b * NT) << 10) + d0 + lane;

    int4 go = goff[bucket];
    int gs = (w == 0) ? go.x : (w == 1) ? go.y : (w == 2) ? go.z : go.w;
    int ge = (w == 3) ? n   : (w == 0) ? go.y : (w == 1) ? go.z : go.w;

    // A-fragments issued early: L3 latency hides under phase A.
    short8 ahi[2], alo[2];
#pragma unroll
    for (int ks = 0; ks < 2; ks++) {
        int idx = ((((w << 1) + ks) << 6) + lane) << 3;
        ahi[ks] = *(const short8*)(AfH + idx);
        alo[ks] = *(const short8*)(AfL + idx);
    }

    // Phase A: per-lane register accumulate over this wave's token group.
    float acc[16];
#pragma unroll
    for (int q = 0; q < 16; q++) acc[q] = 0.f;

    for (int win = gs; win < ge; win += 64) {
        int wn = ge - win; if (wn > 64) wn = 64;        // uniform per wave
        int pkv = toks[win + lane];                     // 1 VMEM: 64 metas
        for (int i = 0; i < wn; i += 8) {
            int m = wn - i; if (m > 8) m = 8;           // uniform
            int pk[8]; float xv[8];
#pragma unroll
            for (int j = 0; j < 8; j++)
                pk[j] = __builtin_amdgcn_readlane(pkv, i + j);   // SGPR
#pragma unroll
            for (int j = 0; j < 8; j++)
                if (j < m) xv[j] = xb[(size_t)(pk[j] & 0xffff) << 10];
#pragma unroll
            for (int j = 0; j < 8; j++) {
                if (j < m) {
                    int phl = (pk[j] >> 16) & 15;       // scalar, [0,16)
#pragma unroll
                    for (int q = 0; q < 16; q++)
                        acc[q] += (q == phl) ? xv[j] : 0.0f;
                }
            }
        }
    }

    // Write bf16 operand tile S16[d=lane][ph=16w+q], packed pairs.
#pragma unroll
    for (int h = 0; h < 8; h++) {
        unsigned int pkd = (unsigned int)f2bf(acc[2 * h])
                         | ((unsigned int)f2bf(acc[2 * h + 1]) << 16);
        *reinterpret_cast<unsigned int*>(&S16[lane][(w << 4) + 2 * h]) = pkd;
    }
    __syncthreads();

    // MFMA: Y[q][d] = (Ghi + Glo) . S16
    int g4 = (lane >> 4) << 2;
    int qbase = (w << 4) + g4;

    f32x4 accs[4];
#pragma unroll
    for (int nt = 0; nt < 4; nt++) {
        const ushort_t* rowp = &S16[(nt << 4) + (lane & 15)][0];
        f32x4 a = {0.f, 0.f, 0.f, 0.f};
#pragma unroll
        for (int ks = 0; ks < 2; ks++) {
            short8 bf = ldsBfrag(rowp, ks, g4);
            a = __builtin_amdgcn_mfma_f32_16x16x32_bf16(ahi[ks], bf, a, 0, 0, 0);
            a = __builtin_amdgcn_mfma_f32_16x16x32_bf16(alo[ks], bf, a, 0, 0, 0);
        }
        accs[nt] = a;
    }
    __syncthreads();                   // all S16 B-fragment reads done

    // Park results (rows=q, cols=d_local), then coalesced store.
#pragma unroll
    for (int nt = 0; nt < 4; nt++)
#pragma unroll
        for (int reg = 0; reg < 4; reg++)
            S16[qbase + reg][(nt << 4) + (lane & 15)] = f2bf(accs[nt][reg]);
    __syncthreads();

    ushort_t* B1p = B1 + (((size_t)(b - b0)) << 22) + (((size_t)pv) << 10) + d0;
#pragma unroll
    for (int pass = 0; pass < 2; pass++) {
        int row = (pass << 5) + (tid >> 3);      // 32 rows per pass
        int col = (tid & 7) << 3;                // 8 ushorts per thread
        uint4 v = *(const uint4*)(&S16[row][col]);
        *reinterpret_cast<uint4*>(B1p + ((size_t)row << 16) + col) = v;
    }
}

// K3: v-conv via MFMA + token scatter (unchanged from round 15).
__global__ __launch_bounds__(256) void k3_convv(
    const int* __restrict__ tokh, const int* __restrict__ cnth,
    const ushort_t* __restrict__ AfH, const ushort_t* __restrict__ AfL,
    const ushort_t* __restrict__ B1, const float* __restrict__ invden,
    float* __restrict__ out, int b0)
{
    int ph   = blockIdx.x & 63;
    int dc   = (blockIdx.x >> 6) & 15;
    int b    = b0 + (blockIdx.x >> 10);
    int tid  = threadIdx.x;
    int lane = tid & 63;
    int w    = tid >> 6;
    int d0   = dc << 6;

    int n = cnth[(b << 6) + ph];
    if (n == 0) return;               // uniform across block

    __shared__ float ldsf[64 * 65];              // 16640 B union buffer
    ushort_t (*u16)[68] = (ushort_t(*)[68])ldsf; // staged B1 column
    float    (*y)[65]   = (float(*)[65])ldsf;    // conv output

    const ushort_t* B1b = B1 + (((size_t)(b - b0)) << 22) + (((size_t)ph) << 16)
                        + d0 + lane;
#pragma unroll
    for (int it = 0; it < 16; it++) {
        int j = (w << 4) + it;
        u16[lane][j] = B1b[(size_t)j << 10];
    }
    __syncthreads();

    short8 ahi[2], alo[2];
#pragma unroll
    for (int ks = 0; ks < 2; ks++) {
        int idx = ((((w << 1) + ks) << 6) + lane) << 3;
        ahi[ks] = *(const short8*)(AfH + idx);
        alo[ks] = *(const short8*)(AfL + idx);
    }
    int g4 = (lane >> 4) << 2;
    int qbase = (w << 4) + g4;

    f32x4 accs[4];
#pragma unroll
    for (int nt = 0; nt < 4; nt++) {
        const ushort_t* rowp = &u16[(nt << 4) + (lane & 15)][0];
        f32x4 a = {0.f, 0.f, 0.f, 0.f};
#pragma unroll
        for (int ks = 0; ks < 2; ks++) {
            short8 bf = ldsBfrag(rowp, ks, g4);
            a = __builtin_amdgcn_mfma_f32_16x16x32_bf16(ahi[ks], bf, a, 0, 0, 0);
            a = __builtin_amdgcn_mfma_f32_16x16x32_bf16(alo[ks], bf, a, 0, 0, 0);
        }
        accs[nt] = a;
    }
    __syncthreads();                   // all u16 reads done before y writes

#pragma unroll
    for (int nt = 0; nt < 4; nt++)
#pragma unroll
        for (int reg = 0; reg < 4; reg++)
            y[qbase + reg][(nt << 4) + (lane & 15)] = accs[nt][reg];
    __syncthreads();

    const int* toks = tokh + ((size_t)((b << 6) + ph)) * CAP;
    float* outb = out + (((size_t)b * NT) << 10) + d0 + lane;
    const float* ivb = invden + ((b << 6) << 6) + ph;

    int nch = (n + 3) >> 2;
    for (int c = w; c < nch; c += 4) {
        int i0 = c << 2;
        int4 M = *(const int4*)(toks + i0);   // safe past n: ws mapped
        int pk[4];
        pk[0] = __builtin_amdgcn_readfirstlane(M.x);
        pk[1] = __builtin_amdgcn_readfirstlane(M.y);
        pk[2] = __builtin_amdgcn_readfirstlane(M.z);
        pk[3] = __builtin_amdgcn_readfirstlane(M.w);
#pragma unroll
        for (int j = 0; j < 4; j++) {
            if (i0 + j < n) {
                int t   = pk[j] & 0xffff;
                int pvt = pk[j] >> 16;
                float iv = ivb[pvt << 6];
                outb[(size_t)t << 10] = y[pvt][lane] * iv;
            }
        }
    }
}

// Safety-net fallback (no workspace needed): direct O(T^2 * D) attention.
__global__ __launch_bounds__(256) void k_naive(
    const float* __restrict__ x, const int* __restrict__ posv,
    const int* __restrict__ posh, float* __restrict__ out)
{
    int t   = blockIdx.x & (NT - 1);
    int b   = blockIdx.x >> 11;
    int tid = threadIdx.x;

    __shared__ float s_w[NT];
    __shared__ float s_red[256];

    int pvt = posv[b * NT + t];
    int pht = posh[b * NT + t];

    float dsum = 0.0f;
    for (int s = tid; s < NT; s += 256) {
        int dv = pvt - posv[b * NT + s];
        int dh = pht - posh[b * NT + s];
        float w = expf(-(float)(dv * dv + dh * dh) * (1.0f / 512.0f));
        s_w[s] = w;
        dsum += w;
    }
    s_red[tid] = dsum;
    __syncthreads();
    for (int off = 128; off > 0; off >>= 1) {
        if (tid < off) s_red[tid] += s_red[tid + off];
        __syncthreads();
    }
    float inv = 1.0f / s_red[0];

    float a0 = 0.f, a1 = 0.f, a2 = 0.f, a3 = 0.f;
    for (int s = 0; s < NT; s++) {
        float w = s_w[s];
        const float* xr = x + (((size_t)(b * NT + s)) << 10);
        a0 = fmaf(w, xr[tid + 0],   a0);
        a1 = fmaf(w, xr[tid + 256], a1);
        a2 = fmaf(w, xr[tid + 512], a2);
        a3 = fmaf(w, xr[tid + 768], a3);
    }
    size_t ob = (((size_t)(b * NT + t)) << 10) + tid;
    out[ob + 0]   = a0 * inv;
    out[ob + 256] = a1 * inv;
    out[ob + 512] = a2 * inv;
    out[ob + 768] = a3 * inv;
}

extern "C" void kernel_launch(void* const* d_in, const int* in_sizes, int n_in,
                              void* d_out, int out_size, void* d_ws, size_t ws_size,
                              hipStream_t stream) {
    const float* x    = (const float*)d_in[0];
    const int*   posv = (const int*)d_in[1];
    const int*   posh = (const int*)d_in[2];
    float*       out  = (float*)d_out;

    char* ws = (char*)d_ws;
    float*    gbase  = (float*)ws;
    ushort_t* AfH    = (ushort_t*)(ws + OFF_AFH);
    ushort_t* AfL    = (ushort_t*)(ws + OFF_AFL);
    int*      cntv   = (int*)(ws + OFF_CNTV);
    int*      cnth   = (int*)(ws + OFF_CNTH);
    float*    invden = (float*)(ws + OFF_INVDEN);
    int4*     goff   = (int4*)(ws + OFF_GOFF);
    int*      tokv   = (int*)(ws + OFF_TOKV);
    int*      tokh   = (int*)(ws + OFF_TOKH);
    int*      tokv2  = (int*)(ws + OFF_TOKV2);
    ushort_t* B1     = (ushort_t*)(ws + OFF_B1);

    const size_t needFull = (size_t)OFF_B1 + (size_t)NB * B1_SLAB;   // ~80 MB
    const size_t needLoop = (size_t)OFF_B1 + B1_SLAB;                // ~21 MB

    if (ws_size >= needFull) {
        // k1 (256 bucket blocks) + fused kden (64 blocks) in one dispatch
        k1_bucket<<<NB * 32 + NB * 8, 256, 0, stream>>>(
            posv, posh, tokv, tokh, cntv, cnth, gbase, AfH, AfL, invden, NB * 32);
        k1b_group<<<NB * 16, 256, 0, stream>>>(tokv, cntv, tokv2, goff);
        k2_convh<<<NB * 1024, 256, 0, stream>>>(x, tokv2, cntv, goff, AfH, AfL, B1, 0);
        k3_convv<<<NB * 1024, 256, 0, stream>>>(tokh, cnth, AfH, AfL, B1, invden, out, 0);
    } else if (ws_size >= needLoop) {
        k1_bucket<<<NB * 32, 256, 0, stream>>>(
            posv, posh, tokv, tokh, cntv, cnth, gbase, AfH, AfL, invden, NB * 32 + 1);
        k1b_group<<<NB * 16, 256, 0, stream>>>(tokv, cntv, tokv2, goff);
        for (int b = 0; b < NB; b++) {
            kden<<<8, 256, 0, stream>>>(posv, posh, invden, b);
            k2_convh<<<1024, 256, 0, stream>>>(x, tokv2, cntv, goff, AfH, AfL, B1, b);
            k3_convv<<<1024, 256, 0, stream>>>(tokh, cnth, AfH, AfL, B1, invden, out, b);
        }
    } else {
        k_naive<<<NB * NT, 256, 0, stream>>>(x, posv, posh, out);
    }
}

// Round 17
// 73.162 us; speedup vs baseline: 2.0775x; 1.0371x over previous
//
#include <hip/hip_runtime.h>
#include <hip/hip_bf16.h>

// Problem constants (fixed by setup_inputs): B=8, T=2048, D=1024, positions in [0,64).
#define NB 8
#define NT 2048
#define ND 1024
#define CAP 2048

typedef unsigned short ushort_t;
using short8 = __attribute__((ext_vector_type(8))) short;   // 8 bf16 (4 VGPR)
using f32x4  = __attribute__((ext_vector_type(4))) float;   // MFMA accum

__device__ __forceinline__ ushort_t f2bf(float f) {
    __hip_bfloat16 h = __float2bfloat16(f);
    return *reinterpret_cast<ushort_t*>(&h);
}
__device__ __forceinline__ float bf2f(ushort_t u) {
    unsigned int v = ((unsigned int)u) << 16;
    return __int_as_float((int)v);
}

// MFMA operand K-slot mapping for 16x16x32 bf16: k(g,i) = (i>>2)*16+4g+(i&3),
// g = lane>>4. Consistent on A-table (k1) and B-reads (k2/k3) -> any
// permutation error cancels over the reduction axis. C/D: col=lane&15,
// row=4*(lane>>4)+reg [HW-verified]. (Validated: rounds 13-16 absmax.)

// ---------------------------------------------------------------------------
// Workspace layout (byte offsets): (tokv slot now unused; tokv2 written by k1)
// ---------------------------------------------------------------------------
#define OFF_G2     256
#define OFF_AFH    768
#define OFF_AFL    8960
#define OFF_CNTV   17152
#define OFF_CNTH   19200
#define OFF_INVDEN 21248
#define OFF_GOFF   152320
#define OFF_TOKV   160512
#define OFF_TOKH   4354816
#define OFF_TOKV2  8549120
#define OFF_B1     12743424
#define B1_SLAB    ((size_t)64 * 64 * 1024 * 2)   // 8 MB per batch (bf16)

// Shared kden body: denominator table via LDS-atomic INTEGER histogram
// (deterministic) + two 64x64 mini-matmuls. g table computed locally.
__device__ __forceinline__ void kden_body(
    int kb, const int* __restrict__ posv, const int* __restrict__ posh,
    float* __restrict__ invden, int b0)
{
    int b   = b0 + (kb >> 3);
    int phg = kb & 7;
    int tid = threadIdx.x;

    __shared__ int   hist[64][64];
    __shared__ float g2s[128];
    __shared__ float tmp[64][8];

#pragma unroll
    for (int k = 0; k < 16; k++) ((int*)hist)[tid + (k << 8)] = 0;
    if (tid < 128) {
        int k = tid, r = k - 63;
        g2s[tid] = (k < 127) ? expf(-(float)(r * r) * (1.0f / 512.0f)) : 0.0f;
    }
    __syncthreads();
#pragma unroll
    for (int k = 0; k < 8; k++) {
        int t = (k << 8) + tid;
        atomicAdd(&hist[posv[b * NT + t]][posh[b * NT + t]], 1);
    }
    __syncthreads();
#pragma unroll
    for (int c = 0; c < 2; c++) {
        int cell = (c << 8) + tid;
        int j    = cell >> 3;
        int phl  = cell & 7;
        int ph   = (phg << 3) + phl;
        float s = 0.f;
        for (int k = 0; k < 64; k++)
            s += (float)hist[j][k] * g2s[63 + k - ph];
        tmp[j][phl] = s;
    }
    __syncthreads();
#pragma unroll
    for (int c = 0; c < 2; c++) {
        int cell = (c << 8) + tid;
        int pv   = cell >> 3;
        int phl  = cell & 7;
        int ph   = (phg << 3) + phl;
        float s = 0.f;
        for (int j = 0; j < 64; j++)
            s += g2s[63 + j - pv] * tmp[j][phl];
        invden[(b * 64 + pv) * 64 + ph] = 1.0f / s;
    }
}

// K1: deterministic bucket lists via wave ballot compaction — round 17:
// the posv-axis list is emitted DIRECTLY grouped by ph>>4 (two-pass
// ballot counting-sort over the in-register candidates), replacing the
// separate k1b dispatch and the tokv round-trip. Block 0 builds the MFMA
// A-fragment tables; blocks >= nbkt run the (independent) kden body.
__global__ __launch_bounds__(256) void k1_bucket(
    const int* __restrict__ posv, const int* __restrict__ posh,
    int* __restrict__ tokv2, int4* __restrict__ goff,
    int* __restrict__ tokh,
    int* __restrict__ cntv, int* __restrict__ cnth,
    float* __restrict__ gbase, ushort_t* __restrict__ AfH,
    ushort_t* __restrict__ AfL, float* __restrict__ invden, int nbkt)
{
    if ((int)blockIdx.x >= nbkt) {            // fused kden blocks
        kden_body((int)blockIdx.x - nbkt, posv, posh, invden, 0);
        return;
    }

    int b    = blockIdx.x >> 5;
    int blk  = blockIdx.x & 31;
    int wave = threadIdx.x >> 6;
    int lane = threadIdx.x & 63;

    if (blockIdx.x == 0) {
        if (threadIdx.x < 192) {
            int k = (int)threadIdx.x - 64;
            float v = 0.0f;
            if (k >= 0 && k < 127) {
                int r = k - 63;
                v = expf(-(float)(r * r) * (1.0f / 512.0f));
            }
            gbase[threadIdx.x] = v;
        }
#pragma unroll
        for (int p = 0; p < 16; p++) {
            int pos = (p << 8) + (int)threadIdx.x;   // 0..4095
            int i   = pos & 7;
            int ln  = (pos >> 3) & 63;
            int ks  = (pos >> 9) & 1;
            int w   = pos >> 10;
            int q   = (w << 4) + (ln & 15);
            int k   = (ks << 5) + ((i >> 2) << 4) + ((ln >> 4) << 2) + (i & 3);
            int dlt = q - k;
            float g = expf(-(float)(dlt * dlt) * (1.0f / 512.0f));
            ushort_t hi = f2bf(g);
            AfH[pos] = hi;
            AfL[pos] = f2bf(g - bf2f(hi));
        }
    }

    int task   = blk * 4 + wave;              // 0..127
    int bucket = task & 63;
    int use_ph = task >> 6;
    int bkt    = b * 64 + bucket;

    // combined per-token meta: posv | posh<<16
    int comb[32];
#pragma unroll
    for (int k = 0; k < 32; k++) {
        int t = k * 64 + lane;
        comb[k] = posv[b * NT + t] | (posh[b * NT + t] << 16);
    }

    unsigned long long lmask = (1ull << lane) - 1ull;

    if (use_ph == 0) {
        // tokv2: tokens with posv==bucket, grouped by ph>>4 (stable order).
        int* dst = tokv2 + (size_t)bkt * CAP;
        int cg0 = 0, cg1 = 0, cg2 = 0, cg3 = 0;
#pragma unroll 4
        for (int k = 0; k < 32; k++) {
            bool hit = (comb[k] & 0xffff) == bucket;
            int grp = (comb[k] >> 20) & 3;
            cg0 += (int)__popcll(__ballot(hit && grp == 0));
            cg1 += (int)__popcll(__ballot(hit && grp == 1));
            cg2 += (int)__popcll(__ballot(hit && grp == 2));
            cg3 += (int)__popcll(__ballot(hit && grp == 3));
        }
        int s1 = cg0, s2 = cg0 + cg1, s3 = cg0 + cg1 + cg2;
        int tot = s3 + cg3;
        if (lane == 0) {
            goff[bkt] = make_int4(0, s1, s2, s3);
            cntv[bkt] = tot;
        }
        int c0 = 0, c1 = s1, c2 = s2, c3 = s3;
#pragma unroll 4
        for (int k = 0; k < 32; k++) {
            bool hit = (comb[k] & 0xffff) == bucket;
            int grp = (comb[k] >> 20) & 3;
            unsigned long long m0 = __ballot(hit && grp == 0);
            unsigned long long m1 = __ballot(hit && grp == 1);
            unsigned long long m2 = __ballot(hit && grp == 2);
            unsigned long long m3 = __ballot(hit && grp == 3);
            if (hit) {
                int p;
                if      (grp == 0) p = c0 + (int)__popcll(m0 & lmask);
                else if (grp == 1) p = c1 + (int)__popcll(m1 & lmask);
                else if (grp == 2) p = c2 + (int)__popcll(m2 & lmask);
                else               p = c3 + (int)__popcll(m3 & lmask);
                dst[p] = (k * 64 + lane) | (comb[k] & 0xffff0000);
            }
            c0 += (int)__popcll(m0); c1 += (int)__popcll(m1);
            c2 += (int)__popcll(m2); c3 += (int)__popcll(m3);
        }
    } else {
        // tokh: tokens with posh==bucket, packed t | posv<<16.
        int* dst = tokh + (size_t)bkt * CAP;
        int cursor = 0;
#pragma unroll 4
        for (int k = 0; k < 32; k++) {
            bool hit = ((comb[k] >> 16) == bucket);
            unsigned long long m = __ballot(hit);
            if (hit)
                dst[cursor + __popcll(m & lmask)] =
                    (k * 64 + lane) | ((comb[k] & 0xffff) << 16);
            cursor += (int)__popcll(m);
        }
        if (lane == 0) cnth[bkt] = cursor;
    }
}

// Standalone kden (loop path only).
__global__ __launch_bounds__(256) void kden(
    const int* __restrict__ posv, const int* __restrict__ posh,
    float* __restrict__ invden, int b0)
{
    kden_body((int)blockIdx.x, posv, posh, invden, b0);
}

// B-fragment load: 8 bf16 at k = ks*32 + {4g..4g+3, 16+4g..16+4g+3}, row n.
__device__ __forceinline__ short8 ldsBfrag(const ushort_t* rowp, int ks, int g4) {
    const ushort_t* p = rowp + (ks << 5) + g4;
    uint2 lo = *(const uint2*)(p);
    uint2 hi = *(const uint2*)(p + 16);
    uint4 pk; pk.x = lo.x; pk.y = lo.y; pk.z = hi.x; pk.w = hi.y;
    return __builtin_bit_cast(short8, pk);
}

// K2: h-conv via MFMA — ROUND-15 STRUCTURE RESTORED (40us measured; the
// round-16 register one-hot was +5us: 32 VALU/token vs ~2 LDS ops).
//   LDS: one 16.6KB union buffer (S fp32 / S16 bf16, barrier-disciplined
//     in-place convert). Phase A RMW is race-free: k1's grouping gives
//     each wave disjoint ph-columns.
//   Prefetch: window-0 meta + first 8 x-gathers issued before LDS zeroing.
__global__ __launch_bounds__(256) void k2_convh(
    const float* __restrict__ x,
    const int* __restrict__ tokv2, const int* __restrict__ cntv,
    const int4* __restrict__ goff,
    const ushort_t* __restrict__ AfH, const ushort_t* __restrict__ AfL,
    ushort_t* __restrict__ B1, int b0)
{
    int pv   = blockIdx.x & 63;
    int dc   = (blockIdx.x >> 6) & 15;
    int b    = b0 + (blockIdx.x >> 10);
    int tid  = threadIdx.x;
    int lane = tid & 63;
    int w    = tid >> 6;
    int d0   = dc << 6;

    __shared__ float ldsf[64 * 65];               // 16640 B union buffer
    float    (*S)[65]   = (float(*)[65])ldsf;     // fp32 accum  S[d][ph]
    ushort_t (*S16)[68] = (ushort_t(*)[68])ldsf;  // bf16 operand / output

    int bucket = (b << 6) + pv;
    int n = cntv[bucket];
    const int* toks = tokv2 + (size_t)bucket * CAP;
    const float* xb = x + (((size_t)b * NT) << 10) + d0 + lane;

    int4 go = goff[bucket];
    int gs = (w == 0) ? go.x : (w == 1) ? go.y : (w == 2) ? go.z : go.w;
    int ge = (w == 3) ? n   : (w == 0) ? go.y : (w == 1) ? go.z : go.w;

    // --- prefetch window 0 (meta + first 8 gathers) before LDS zeroing ---
    int wn0 = ge - gs; if (wn0 < 0) wn0 = 0; if (wn0 > 64) wn0 = 64;
    int m0  = wn0 > 8 ? 8 : wn0;
    int pkv = (wn0 > 0) ? toks[gs + lane] : 0;
    int pk0[8]; float xv0[8];
#pragma unroll
    for (int j = 0; j < 8; j++) pk0[j] = __builtin_amdgcn_readlane(pkv, j);
#pragma unroll
    for (int j = 0; j < 8; j++)
        if (j < m0) xv0[j] = xb[(size_t)(pk0[j] & 0xffff) << 10];

    // zero S while the loads are in flight
#pragma unroll
    for (int k = 0; k < 17; k++) {
        int idx = (k << 8) + tid;
        if (idx < 64 * 65) ldsf[idx] = 0.f;
    }
    __syncthreads();

    // consume prefetched batch
#pragma unroll
    for (int j = 0; j < 8; j++)
        if (j < m0) S[lane][pk0[j] >> 16] += xv0[j];

    // rest of window 0
    for (int i = 8; i < wn0; i += 8) {
        int m = wn0 - i; if (m > 8) m = 8;
        int pk[8]; float xv[8];
#pragma unroll
        for (int j = 0; j < 8; j++) pk[j] = __builtin_amdgcn_readlane(pkv, i + j);
#pragma unroll
        for (int j = 0; j < 8; j++)
            if (j < m) xv[j] = xb[(size_t)(pk[j] & 0xffff) << 10];
#pragma unroll
        for (int j = 0; j < 8; j++)
            if (j < m) S[lane][pk[j] >> 16] += xv[j];
    }
    // windows 1.. (rare: wave-group >64 tokens)
    for (int win = gs + 64; win < ge; win += 64) {
        int wn = ge - win; if (wn > 64) wn = 64;
        int pkw = toks[win + lane];
        for (int i = 0; i < wn; i += 8) {
            int m = wn - i; if (m > 8) m = 8;
            int pk[8]; float xv[8];
#pragma unroll
            for (int j = 0; j < 8; j++) pk[j] = __builtin_amdgcn_readlane(pkw, i + j);
#pragma unroll
            for (int j = 0; j < 8; j++)
                if (j < m) xv[j] = xb[(size_t)(pk[j] & 0xffff) << 10];
#pragma unroll
            for (int j = 0; j < 8; j++)
                if (j < m) S[lane][pk[j] >> 16] += xv[j];
        }
    }
    __syncthreads();

    // in-place fp32 -> bf16 convert (read to regs, barrier, aliased write)
    {
        int r  = tid & 63;
        int c0 = (tid >> 6) << 4;
        float vals[16];
#pragma unroll
        for (int c = 0; c < 16; c++) vals[c] = S[r][c0 + c];
        __syncthreads();
#pragma unroll
        for (int c = 0; c < 16; c++) S16[r][c0 + c] = f2bf(vals[c]);
    }
    __syncthreads();

    // MFMA: Y[q][d] = (Ghi + Glo) . S16
    short8 ahi[2], alo[2];
#pragma unroll
    for (int ks = 0; ks < 2; ks++) {
        int idx = ((((w << 1) + ks) << 6) + lane) << 3;
        ahi[ks] = *(const short8*)(AfH + idx);
        alo[ks] = *(const short8*)(AfL + idx);
    }
    int g4 = (lane >> 4) << 2;
    int qbase = (w << 4) + g4;

    f32x4 accs[4];
#pragma unroll
    for (int nt = 0; nt < 4; nt++) {
        const ushort_t* rowp = &S16[(nt << 4) + (lane & 15)][0];
        f32x4 a = {0.f, 0.f, 0.f, 0.f};
#pragma unroll
        for (int ks = 0; ks < 2; ks++) {
            short8 bf = ldsBfrag(rowp, ks, g4);
            a = __builtin_amdgcn_mfma_f32_16x16x32_bf16(ahi[ks], bf, a, 0, 0, 0);
            a = __builtin_amdgcn_mfma_f32_16x16x32_bf16(alo[ks], bf, a, 0, 0, 0);
        }
        accs[nt] = a;
    }
    __syncthreads();                   // all S16 B-fragment reads done

    // Park results (rows=q, cols=d_local), then coalesced store.
#pragma unroll
    for (int nt = 0; nt < 4; nt++)
#pragma unroll
        for (int reg = 0; reg < 4; reg++)
            S16[qbase + reg][(nt << 4) + (lane & 15)] = f2bf(accs[nt][reg]);
    __syncthreads();

    ushort_t* B1p = B1 + (((size_t)(b - b0)) << 22) + (((size_t)pv) << 10) + d0;
#pragma unroll
    for (int pass = 0; pass < 2; pass++) {
        int row = (pass << 5) + (tid >> 3);      // 32 rows per pass
        int col = (tid & 7) << 3;                // 8 ushorts per thread
        uint4 v = *(const uint4*)(&S16[row][col]);
        *reinterpret_cast<uint4*>(B1p + ((size_t)row << 16) + col) = v;
    }
}

// K3: v-conv via MFMA + token scatter (unchanged — near traffic floor).
__global__ __launch_bounds__(256) void k3_convv(
    const int* __restrict__ tokh, const int* __restrict__ cnth,
    const ushort_t* __restrict__ AfH, const ushort_t* __restrict__ AfL,
    const ushort_t* __restrict__ B1, const float* __restrict__ invden,
    float* __restrict__ out, int b0)
{
    int ph   = blockIdx.x & 63;
    int dc   = (blockIdx.x >> 6) & 15;
    int b    = b0 + (blockIdx.x >> 10);
    int tid  = threadIdx.x;
    int lane = tid & 63;
    int w    = tid >> 6;
    int d0   = dc << 6;

    int n = cnth[(b << 6) + ph];
    if (n == 0) return;               // uniform across block

    __shared__ float ldsf[64 * 65];              // 16640 B union buffer
    ushort_t (*u16)[68] = (ushort_t(*)[68])ldsf; // staged B1 column
    float    (*y)[65]   = (float(*)[65])ldsf;    // conv output

    const ushort_t* B1b = B1 + (((size_t)(b - b0)) << 22) + (((size_t)ph) << 16)
                        + d0 + lane;
#pragma unroll
    for (int it = 0; it < 16; it++) {
        int j = (w << 4) + it;
        u16[lane][j] = B1b[(size_t)j << 10];
    }
    __syncthreads();

    short8 ahi[2], alo[2];
#pragma unroll
    for (int ks = 0; ks < 2; ks++) {
        int idx = ((((w << 1) + ks) << 6) + lane) << 3;
        ahi[ks] = *(const short8*)(AfH + idx);
        alo[ks] = *(const short8*)(AfL + idx);
    }
    int g4 = (lane >> 4) << 2;
    int qbase = (w << 4) + g4;

    f32x4 accs[4];
#pragma unroll
    for (int nt = 0; nt < 4; nt++) {
        const ushort_t* rowp = &u16[(nt << 4) + (lane & 15)][0];
        f32x4 a = {0.f, 0.f, 0.f, 0.f};
#pragma unroll
        for (int ks = 0; ks < 2; ks++) {
            short8 bf = ldsBfrag(rowp, ks, g4);
            a = __builtin_amdgcn_mfma_f32_16x16x32_bf16(ahi[ks], bf, a, 0, 0, 0);
            a = __builtin_amdgcn_mfma_f32_16x16x32_bf16(alo[ks], bf, a, 0, 0, 0);
        }
        accs[nt] = a;
    }
    __syncthreads();                   // all u16 reads done before y writes

#pragma unroll
    for (int nt = 0; nt < 4; nt++)
#pragma unroll
        for (int reg = 0; reg < 4; reg++)
            y[qbase + reg][(nt << 4) + (lane & 15)] = accs[nt][reg];
    __syncthreads();

    const int* toks = tokh + ((size_t)((b << 6) + ph)) * CAP;
    float* outb = out + (((size_t)b * NT) << 10) + d0 + lane;
    const float* ivb = invden + ((b << 6) << 6) + ph;

    int nch = (n + 3) >> 2;
    for (int c = w; c < nch; c += 4) {
        int i0 = c << 2;
        int4 M = *(const int4*)(toks + i0);   // safe past n: ws mapped
        int pk[4];
        pk[0] = __builtin_amdgcn_readfirstlane(M.x);
        pk[1] = __builtin_amdgcn_readfirstlane(M.y);
        pk[2] = __builtin_amdgcn_readfirstlane(M.z);
        pk[3] = __builtin_amdgcn_readfirstlane(M.w);
#pragma unroll
        for (int j = 0; j < 4; j++) {
            if (i0 + j < n) {
                int t   = pk[j] & 0xffff;
                int pvt = pk[j] >> 16;
                float iv = ivb[pvt << 6];
                outb[(size_t)t << 10] = y[pvt][lane] * iv;
            }
        }
    }
}

// Safety-net fallback (no workspace needed): direct O(T^2 * D) attention.
__global__ __launch_bounds__(256) void k_naive(
    const float* __restrict__ x, const int* __restrict__ posv,
    const int* __restrict__ posh, float* __restrict__ out)
{
    int t   = blockIdx.x & (NT - 1);
    int b   = blockIdx.x >> 11;
    int tid = threadIdx.x;

    __shared__ float s_w[NT];
    __shared__ float s_red[256];

    int pvt = posv[b * NT + t];
    int pht = posh[b * NT + t];

    float dsum = 0.0f;
    for (int s = tid; s < NT; s += 256) {
        int dv = pvt - posv[b * NT + s];
        int dh = pht - posh[b * NT + s];
        float w = expf(-(float)(dv * dv + dh * dh) * (1.0f / 512.0f));
        s_w[s] = w;
        dsum += w;
    }
    s_red[tid] = dsum;
    __syncthreads();
    for (int off = 128; off > 0; off >>= 1) {
        if (tid < off) s_red[tid] += s_red[tid + off];
        __syncthreads();
    }
    float inv = 1.0f / s_red[0];

    float a0 = 0.f, a1 = 0.f, a2 = 0.f, a3 = 0.f;
    for (int s = 0; s < NT; s++) {
        float w = s_w[s];
        const float* xr = x + (((size_t)(b * NT + s)) << 10);
        a0 = fmaf(w, xr[tid + 0],   a0);
        a1 = fmaf(w, xr[tid + 256], a1);
        a2 = fmaf(w, xr[tid + 512], a2);
        a3 = fmaf(w, xr[tid + 768], a3);
    }
    size_t ob = (((size_t)(b * NT + t)) << 10) + tid;
    out[ob + 0]   = a0 * inv;
    out[ob + 256] = a1 * inv;
    out[ob + 512] = a2 * inv;
    out[ob + 768] = a3 * inv;
}

extern "C" void kernel_launch(void* const* d_in, const int* in_sizes, int n_in,
                              void* d_out, int out_size, void* d_ws, size_t ws_size,
                              hipStream_t stream) {
    const float* x    = (const float*)d_in[0];
    const int*   posv = (const int*)d_in[1];
    const int*   posh = (const int*)d_in[2];
    float*       out  = (float*)d_out;

    char* ws = (char*)d_ws;
    float*    gbase  = (float*)ws;
    ushort_t* AfH    = (ushort_t*)(ws + OFF_AFH);
    ushort_t* AfL    = (ushort_t*)(ws + OFF_AFL);
    int*      cntv   = (int*)(ws + OFF_CNTV);
    int*      cnth   = (int*)(ws + OFF_CNTH);
    float*    invden = (float*)(ws + OFF_INVDEN);
    int4*     goff   = (int4*)(ws + OFF_GOFF);
    int*      tokh   = (int*)(ws + OFF_TOKH);
    int*      tokv2  = (int*)(ws + OFF_TOKV2);
    ushort_t* B1     = (ushort_t*)(ws + OFF_B1);

    const size_t needFull = (size_t)OFF_B1 + (size_t)NB * B1_SLAB;   // ~80 MB
    const size_t needLoop = (size_t)OFF_B1 + B1_SLAB;                // ~21 MB

    if (ws_size >= needFull) {
        // k1 (256 bucket blocks, emits grouped tokv2 directly) + fused kden
        k1_bucket<<<NB * 32 + NB * 8, 256, 0, stream>>>(
            posv, posh, tokv2, goff, tokh, cntv, cnth, gbase, AfH, AfL,
            invden, NB * 32);
        k2_convh<<<NB * 1024, 256, 0, stream>>>(x, tokv2, cntv, goff, AfH, AfL, B1, 0);
        k3_convv<<<NB * 1024, 256, 0, stream>>>(tokh, cnth, AfH, AfL, B1, invden, out, 0);
    } else if (ws_size >= needLoop) {
        k1_bucket<<<NB * 32, 256, 0, stream>>>(
            posv, posh, tokv2, goff, tokh, cntv, cnth, gbase, AfH, AfL,
            invden, NB * 32);
        for (int b = 0; b < NB; b++) {
            kden<<<8, 256, 0, stream>>>(posv, posh, invden, b);
            k2_convh<<<1024, 256, 0, stream>>>(x, tokv2, cntv, goff, AfH, AfL, B1, b);
            k3_convv<<<1024, 256, 0, stream>>>(tokh, cnth, AfH, AfL, B1, invden, out, b);
        }
    } else {
        k_naive<<<NB * NT, 256, 0, stream>>>(x, posv, posh, out);
    }
}